// Round 8
// baseline (11829.493 us; speedup 1.0000x reference)
//
#include <hip/hip_runtime.h>
#include <math.h>

// ---------------- problem constants ----------------
#define BATCH 256
#define TLEN  519          // W + MAXLAG
#define WIN   512
#define HID   256
#define PRED  24
#define NS    100
#define NLAG  7
#define GROWS (BATCH * NS) // 25600 decoder rows
#define TCHUNK 128         // encoder time chunk (4 chunks of 128)

// ---------------- workspace layout (float/uint offsets) ----------------
#define OFF_SCALED 0
#define OFF_LOC    132864
#define OFF_SCALE  133120
#define OFF_WIH0   133376   // fp32 [f][j][q], f<7  (encoder lag weights)
#define OFF_WHH0H  140544   // half2 [p][j][q], p<128 (encoder L0 recurrent)
#define OFF_WCAT1H 271616   // half2 [p][j][q], p<256 (p>=128 = w_hh1, enc1 recurrent)
#define OFF_B0     533760   // fp32 combined b_ih0+b_hh0, [j][q]
#define OFF_B1     534784
#define OFF_BN0    535808   // fp32 bias by MFMA col n (layer0)
#define OFF_BN1    536832
#define OFF_F0     537856   // fp16 B-fragments layer0: 9 ks x 64 nt x 64 lane x 8
#define OFF_F1     685312   // fp16 B-fragments layer1: 16 ks x 64 nt x 64 lane x 8
#define OFF_EH0    947456   // encoder states fp32 [b][j] (chunk-carried)
#define OFF_EC0    1012992
#define OFF_EH1    1078528
#define OFF_EC1    1144064
#define OFF_ACC    1209600  // sample accumulators [b][p]
#define OFF_TRAJ   1215744  // fp16 h0 trajectory [b][tl<128][256] = 16.8 MB
#define WS_FLOATS  5410048  // 21.6 MB

// ---------------- helpers ----------------
typedef _Float16 h2_t  __attribute__((ext_vector_type(2)));
typedef _Float16 half8 __attribute__((ext_vector_type(8)));
typedef float    f32x4 __attribute__((ext_vector_type(4)));

__device__ __forceinline__ float sigm(float x) { return 1.0f / (1.0f + __expf(-x)); }
__device__ __forceinline__ float ftanh(float x) {
    float e = __expf(2.0f * x);
    return 1.0f - 2.0f / (e + 1.0f);
}
__device__ __forceinline__ float softplus(float x) {
    return (x > 15.0f) ? x : log1pf(__expf(x));
}
__device__ __forceinline__ void fma4(float4& a, const float4 w, const float x) {
    a.x = fmaf(w.x, x, a.x);
    a.y = fmaf(w.y, x, a.y);
    a.z = fmaf(w.z, x, a.z);
    a.w = fmaf(w.w, x, a.w);
}
__device__ __forceinline__ float dot2(unsigned int h, unsigned int w, float acc) {
    return __builtin_amdgcn_fdot2(__builtin_bit_cast(h2_t, h),
                                  __builtin_bit_cast(h2_t, w), acc, false);
}
__device__ __forceinline__ void dot2x4(float4& a, const unsigned int h, const uint4 w) {
    a.x = dot2(h, w.x, a.x);
    a.y = dot2(h, w.y, a.y);
    a.z = dot2(h, w.z, a.z);
    a.w = dot2(h, w.w, a.w);
}
__device__ __forceinline__ unsigned int packh2(float a, float b) {
    h2_t h;
    h.x = (_Float16)a;
    h.y = (_Float16)b;
    return __builtin_bit_cast(unsigned int, h);
}
__device__ __forceinline__ unsigned short hbits(float v) {
    return __builtin_bit_cast(unsigned short, (_Float16)v);
}

// ---------------- kernel 1: repack weights ----------------
__global__ __launch_bounds__(256) void prep_weights(
    const float* __restrict__ w_ih0, const float* __restrict__ w_hh0,
    const float* __restrict__ b_ih0, const float* __restrict__ b_hh0,
    const float* __restrict__ w_ih1, const float* __restrict__ w_hh1,
    const float* __restrict__ b_ih1, const float* __restrict__ b_hh1,
    float* __restrict__ ws) {
    int id = blockIdx.x * blockDim.x + threadIdx.x;   // grid covers 262144
    unsigned int* wsu = (unsigned int*)ws;
    // ---- encoder layouts ----
    {
        int g4 = id & 1023;
        int jj = g4 >> 2, q = g4 & 3;
        int grow = q * HID + jj;
        int p = id >> 10;
        int k0 = 2 * p;
        float v0, v1;
        if (k0 < 256) { v0 = w_ih1[grow * HID + k0];       v1 = w_ih1[grow * HID + k0 + 1]; }
        else          { v0 = w_hh1[grow * HID + k0 - 256]; v1 = w_hh1[grow * HID + k0 - 255]; }
        wsu[OFF_WCAT1H + id] = packh2(v0, v1);
        if (id < 131072) {
            wsu[OFF_WHH0H + id] = packh2(w_hh0[grow * HID + 2 * p], w_hh0[grow * HID + 2 * p + 1]);
        }
        if (id < 7168) {
            int f = id >> 10;
            ws[OFF_WIH0 + id] = w_ih0[grow * NLAG + f];
        }
        if (id < 1024) {
            ws[OFF_B0 + id] = b_ih0[grow] + b_hh0[grow];
            ws[OFF_B1 + id] = b_ih1[grow] + b_hh1[grow];
        }
    }
    // ---- decoder/enc1 biases by MFMA col ----
    if (id < 2048) {
        int n = id & 1023;
        int w = n >> 8, u = (n >> 2) & 63, q = n & 3;
        int grow = q * HID + w * 64 + u;
        if (id < 1024) ws[OFF_BN0 + n] = b_ih0[grow] + b_hh0[grow];
        else           ws[OFF_BN1 + n] = b_ih1[grow] + b_hh1[grow];
    }
    // ---- F0 fragments: 9 ks (ks0 = lag block) ----
    if (id < 36864) {
        int ks = id / 4096, rem = id % 4096, nt = rem >> 6, l = rem & 63;
        int n = nt * 16 + (l & 15);
        int w = n >> 8, u = (n >> 2) & 63, q = n & 3;
        int grow = q * HID + w * 64 + u;
        int kbase = (l >> 4) * 8;
        unsigned short h8[8];
        #pragma unroll
        for (int i = 0; i < 8; ++i) {
            float v;
            if (ks == 0) { int k = kbase + i; v = (k < NLAG) ? w_ih0[grow * NLAG + k] : 0.0f; }
            else         { int kk = (ks - 1) * 32 + kbase + i; v = w_hh0[grow * HID + kk]; }
            h8[i] = hbits(v);
        }
        uint4 o;
        o.x = (unsigned int)h8[0] | ((unsigned int)h8[1] << 16);
        o.y = (unsigned int)h8[2] | ((unsigned int)h8[3] << 16);
        o.z = (unsigned int)h8[4] | ((unsigned int)h8[5] << 16);
        o.w = (unsigned int)h8[6] | ((unsigned int)h8[7] << 16);
        ((uint4*)(ws + OFF_F0))[id] = o;
    }
    // ---- F1 fragments: 16 ks (ks<8 = w_ih1, used by enc1 MFMA + decoder) ----
    if (id < 65536) {
        int ks = id >> 12, rem = id & 4095, nt = rem >> 6, l = rem & 63;
        int n = nt * 16 + (l & 15);
        int w = n >> 8, u = (n >> 2) & 63, q = n & 3;
        int grow = q * HID + w * 64 + u;
        int kbase = (l >> 4) * 8;
        unsigned short h8[8];
        #pragma unroll
        for (int i = 0; i < 8; ++i) {
            int kk = ks * 32 + kbase + i;
            float v = (kk < 256) ? w_ih1[grow * HID + kk] : w_hh1[grow * HID + kk - 256];
            h8[i] = hbits(v);
        }
        uint4 o;
        o.x = (unsigned int)h8[0] | ((unsigned int)h8[1] << 16);
        o.y = (unsigned int)h8[2] | ((unsigned int)h8[3] << 16);
        o.z = (unsigned int)h8[4] | ((unsigned int)h8[5] << 16);
        o.w = (unsigned int)h8[6] | ((unsigned int)h8[7] << 16);
        ((uint4*)(ws + OFF_F1))[id] = o;
    }
}

// ---------------- kernel 2: normalize + zero accumulators ----------------
__global__ __launch_bounds__(256) void prep_norm(const float* __restrict__ x,
                                                 float* __restrict__ ws) {
    const int b = blockIdx.x, j = threadIdx.x;
    const float* row = x + b * TLEN;
    float s = 0.0f, s2 = 0.0f;
    for (int t = j; t < WIN; t += 256) {
        float v = row[NLAG + t];
        s += v;
        s2 = fmaf(v, v, s2);
    }
    #pragma unroll
    for (int off = 32; off > 0; off >>= 1) {
        s  += __shfl_down(s, off, 64);
        s2 += __shfl_down(s2, off, 64);
    }
    __shared__ float rs[4], rs2[4];
    __shared__ float sh_loc, sh_scale;
    int wave = j >> 6, lane = j & 63;
    if (lane == 0) { rs[wave] = s; rs2[wave] = s2; }
    __syncthreads();
    if (j == 0) {
        float S = rs[0] + rs[1] + rs[2] + rs[3];
        float S2 = rs2[0] + rs2[1] + rs2[2] + rs2[3];
        float mean = S * (1.0f / WIN);
        float var = S2 * (1.0f / WIN) - mean * mean;
        float sd = sqrtf(fmaxf(var, 0.0f));
        if (sd < 1e-10f) sd = 1.0f;
        sh_loc = mean; sh_scale = sd;
        ws[OFF_LOC + b] = mean;
        ws[OFF_SCALE + b] = sd;
    }
    __syncthreads();
    float loc = sh_loc, inv = 1.0f / sh_scale;
    for (int t = j; t < TLEN; t += 256) {
        ws[OFF_SCALED + b * TLEN + t] = (row[t] - loc) * inv;
    }
    if (j < PRED) ws[OFF_ACC + b * PRED + j] = 0.0f;
}

// ---------------- kernel 3a: encoder L0 phase (one 128-step chunk) ----------------
// 128 blocks x 1024 threads, 2 rows/block, 4-way in-block k-split over w_hh0
// ONLY (512 KB/step vs r7's 1.57 MB: w_ih1 moved to enc1's MFMA batch).
// Writes the h0 trajectory (fp16, chunk-local) for enc1's A-operand.
__global__ __launch_bounds__(1024) void enc0_kernel(float* __restrict__ ws, int tc) {
    const int tid = threadIdx.x;
    const int j  = tid & 255;      // unit
    const int kq = tid >> 8;       // k-quarter (0..3)
    const int bb = blockIdx.x;     // 0..127
    __shared__ unsigned int h0p[2][128];
    __shared__ float4 pgs[2][4][256];
    __shared__ float4 wlag[NLAG * 256];   // lag weights fp32 (28 KB)
    __shared__ float xs[2][NLAG];
    float c0[2] = {0.0f, 0.0f};

    for (int i = tid; i < NLAG * 256; i += 1024)
        wlag[i] = ((const float4*)(ws + OFF_WIH0))[i];
    const uint4* W0 = (const uint4*)((const unsigned int*)ws + OFF_WHH0H);
    float4 bv0 = {0, 0, 0, 0};
    if (kq == 0) {
        bv0 = ((const float4*)(ws + OFF_B0))[j];
        #pragma unroll
        for (int r = 0; r < 2; ++r) {
            int b = bb * 2 + r;
            if (tc == 0) {
                c0[r] = 0.0f;
                ((_Float16*)&h0p[r][0])[j] = (_Float16)0.0f;
            } else {
                c0[r] = ws[OFF_EC0 + b * HID + j];
                ((_Float16*)&h0p[r][0])[j] = (_Float16)ws[OFF_EH0 + b * HID + j];
            }
        }
    }
    const float* sc0 = ws + OFF_SCALED + (bb * 2 + 0) * TLEN;
    const float* sc1 = ws + OFF_SCALED + (bb * 2 + 1) * TLEN;
    _Float16* traj = (_Float16*)(ws + OFF_TRAJ);
    __syncthreads();

    for (int tl = 0; tl < TCHUNK; ++tl) {
        int t = tc + tl;
        if (tid < 2 * NLAG) {
            int r = tid / NLAG, f = tid % NLAG;
            xs[r][f] = (r ? sc1 : sc0)[t + 6 - f];
        }
        // L0 partials: 32 k-pairs per quarter
        {
            float4 a0 = {0, 0, 0, 0}, a1 = {0, 0, 0, 0};
            const uint4* Wp = W0 + (kq * 32) * 256 + j;
            const unsigned int* hp0 = &h0p[0][kq * 32];
            const unsigned int* hp1 = &h0p[1][kq * 32];
            #pragma unroll 4
            for (int p = 0; p < 32; ++p) {
                uint4 w = Wp[p * 256];
                dot2x4(a0, hp0[p], w);
                dot2x4(a1, hp1[p], w);
            }
            pgs[0][kq][j] = a0;
            pgs[1][kq][j] = a1;
        }
        __syncthreads();   // pgs + xs ready; L0 reads of h0p done
        if (kq == 0) {
            #pragma unroll
            for (int r = 0; r < 2; ++r) {
                float4 a = bv0;
                #pragma unroll
                for (int f = 0; f < NLAG; ++f) fma4(a, wlag[f * 256 + j], xs[r][f]);
                #pragma unroll
                for (int h = 0; h < 4; ++h) {
                    float4 p = pgs[r][h][j];
                    a.x += p.x; a.y += p.y; a.z += p.z; a.w += p.w;
                }
                c0[r] = sigm(a.y) * c0[r] + sigm(a.x) * ftanh(a.z);
                _Float16 hh = (_Float16)(sigm(a.w) * ftanh(c0[r]));
                ((_Float16*)&h0p[r][0])[j] = hh;
                traj[((bb * 2 + r) * TCHUNK + tl) * HID + j] = hh;
            }
        }
        __syncthreads();   // h0p(t) visible
    }
    if (kq == 0) {
        #pragma unroll
        for (int r = 0; r < 2; ++r) {
            int b = bb * 2 + r;
            ws[OFF_EH0 + b * HID + j] = (float)((_Float16*)&h0p[r][0])[j];
            ws[OFF_EC0 + b * HID + j] = c0[r];
        }
    }
}

// ---------------- kernel 3b: encoder L1 phase (one 128-step chunk) ----------------
// 128 blocks x 1024 threads, 2 rows/block. Per 8-step group: one MFMA batch
// (M=16 = 2 rows x 8 steps) computes P = h0 @ w_ih1^T + bias into LDS using
// the decoder's F1 fragments (ks<8) — amortizes w_ih1's 512 KB over 8 steps.
// Then 8 sequential sub-steps stream only w_hh1 (512 KB/step, 4-way k-split).
__global__ __launch_bounds__(1024) void enc1_kernel(float* __restrict__ ws, int tc) {
    const int tid = threadIdx.x;
    const int lane = tid & 63, wv = tid >> 6;   // 16 waves
    const int j  = tid & 255;
    const int kq = tid >> 8;
    const int bb = blockIdx.x;
    const int m16 = lane & 15, q16 = lane >> 4;
    __shared__ float P[16][1028];          // [m = r*8+ss][gate col n], 65.8 KB
    __shared__ float4 pgs[2][4][256];      // 32 KB
    __shared__ unsigned int h1p[2][128];
    float c1[2] = {0.0f, 0.0f};

    const uint4* F1 = (const uint4*)(ws + OFF_F1);
    const uint4* W1 = (const uint4*)((const unsigned int*)ws + OFF_WCAT1H);
    const float* bn1 = ws + OFF_BN1;
    const _Float16* traj = (const _Float16*)(ws + OFF_TRAJ);

    if (kq == 0) {
        #pragma unroll
        for (int r = 0; r < 2; ++r) {
            int b = bb * 2 + r;
            if (tc == 0) {
                c1[r] = 0.0f;
                ((_Float16*)&h1p[r][0])[j] = (_Float16)0.0f;
            } else {
                c1[r] = ws[OFF_EC1 + b * HID + j];
                ((_Float16*)&h1p[r][0])[j] = (_Float16)ws[OFF_EH1 + b * HID + j];
            }
        }
    }
    __syncthreads();

    for (int g8 = 0; g8 < TCHUNK / 8; ++g8) {
        // ---- MFMA batch: P[m][n] = bias + sum_k h0[m][k] * w_ih1[n][k] ----
        {
            const int ntb = wv * 4;   // this wave's 4 n-tiles
            f32x4 acc[4];
            #pragma unroll
            for (int qq = 0; qq < 4; ++qq) {
                float b = bn1[(ntb + qq) * 16 + m16];
                acc[qq] = (f32x4){b, b, b, b};
            }
            #pragma unroll
            for (int ks = 0; ks < 8; ++ks) {
                const _Float16* ap = traj +
                    (((bb * 2 + (m16 >> 3)) * TCHUNK) + g8 * 8 + (m16 & 7)) * HID +
                    q16 * 8 + ks * 32;
                half8 av = *(const half8*)ap;
                #pragma unroll
                for (int qq = 0; qq < 4; ++qq) {
                    uint4 bw = F1[(ks * 64 + ntb + qq) * 64 + lane];
                    acc[qq] = __builtin_amdgcn_mfma_f32_16x16x32_f16(
                        av, __builtin_bit_cast(half8, bw), acc[qq], 0, 0, 0);
                }
            }
            #pragma unroll
            for (int qq = 0; qq < 4; ++qq)
                #pragma unroll
                for (int rg = 0; rg < 4; ++rg)
                    P[q16 * 4 + rg][(ntb + qq) * 16 + m16] = acc[qq][rg];
        }
        __syncthreads();   // P ready; also guards P overwrite vs prior reads
        // ---- 8 sequential sub-steps: recurrent w_hh1 only ----
        for (int ss = 0; ss < 8; ++ss) {
            {
                float4 a0 = {0, 0, 0, 0}, a1 = {0, 0, 0, 0};
                const uint4* Wp = W1 + (128 + kq * 32) * 256 + j;
                const unsigned int* hp0 = &h1p[0][kq * 32];
                const unsigned int* hp1 = &h1p[1][kq * 32];
                #pragma unroll 4
                for (int p = 0; p < 32; ++p) {
                    uint4 w = Wp[p * 256];
                    dot2x4(a0, hp0[p], w);
                    dot2x4(a1, hp1[p], w);
                }
                pgs[0][kq][j] = a0;
                pgs[1][kq][j] = a1;
            }
            __syncthreads();   // pgs ready; reads of h1p done
            if (kq == 0) {
                #pragma unroll
                for (int r = 0; r < 2; ++r) {
                    int m = r * 8 + ss;
                    float4 a = *(const float4*)&P[m][j * 4];
                    #pragma unroll
                    for (int h = 0; h < 4; ++h) {
                        float4 p = pgs[r][h][j];
                        a.x += p.x; a.y += p.y; a.z += p.z; a.w += p.w;
                    }
                    c1[r] = sigm(a.y) * c1[r] + sigm(a.x) * ftanh(a.z);
                    ((_Float16*)&h1p[r][0])[j] = (_Float16)(sigm(a.w) * ftanh(c1[r]));
                }
            }
            __syncthreads();   // h1p(t) visible
        }
    }
    if (kq == 0) {
        #pragma unroll
        for (int r = 0; r < 2; ++r) {
            int b = bb * 2 + r;
            ws[OFF_EH1 + b * HID + j] = (float)((_Float16*)&h1p[r][0])[j];
            ws[OFF_EC1 + b * HID + j] = c1[r];
        }
    }
}

// ---------------- kernel 4: MFMA decoder (r4-verified, RDEC=32, 3 blocks/CU) ----------------
// LDS 53248 B x 3 = 159744 <= 163840 -> (256,3) admits a 3rd block/CU
// (VGPR 128 <= 170 cap). Decoder is latency-bound (45 GB/s/CU of 131) —
// occupancy is the lever.
#define RDEC 32
__global__ __launch_bounds__(256, 3) void decoder_kernel(
    const float* __restrict__ wsr,
    const float* __restrict__ w_mu, const float* __restrict__ b_mu,
    const float* __restrict__ w_sigma, const float* __restrict__ b_sigma,
    const float* __restrict__ eps, float* __restrict__ wsw) {
    const int j = threadIdx.x, lane = j & 63, wv = j >> 6;
    const int gr0 = blockIdx.x * RDEC;
    const int m16 = lane & 15, q16 = lane >> 4;
    __shared__ _Float16 hA[2][RDEC][264];   // [layer][row][unit], pad to 264
    __shared__ _Float16 xlag[RDEC][32];     // lag A-tile (k 0..6 live, rest 0)
    __shared__ float scr[4][16][68];        // per-wave D transpose scratch

    const uint4* F0 = (const uint4*)(wsr + OFF_F0);
    const uint4* F1 = (const uint4*)(wsr + OFF_F1);
    const float* bn0 = wsr + OFF_BN0;
    const float* bn1 = wsr + OFF_BN1;

    float c0r[8][4], c1r[8][4];
    for (int r = 0; r < RDEC; ++r) {
        int b = (gr0 + r) / NS;
        hA[0][r][j] = (_Float16)wsr[OFF_EH0 + b * HID + j];
        hA[1][r][j] = (_Float16)wsr[OFF_EH1 + b * HID + j];
    }
    { int r = j >> 3, p = j & 7;
      hA[0][r][256 + p] = (_Float16)0.0f; hA[1][r][256 + p] = (_Float16)0.0f; }
    #pragma unroll
    for (int it = 0; it < 4; ++it) {
        int idx = j + 256 * it;
        int r = idx >> 5, k = idx & 31;
        int b = (gr0 + r) / NS;
        xlag[r][k] = (k < NLAG) ? (_Float16)wsr[OFF_SCALED + b * TLEN + WIN + 6 - k]
                                : (_Float16)0.0f;
    }
    #pragma unroll
    for (int Q = 0; Q < 4; ++Q)
        #pragma unroll
        for (int mt = 0; mt < 2; ++mt) {
            int t2 = Q * 2 + mt;
            int b = (gr0 + mt * 16 + m16) / NS;
            #pragma unroll
            for (int i = 0; i < 4; ++i) {
                int jg = wv * 64 + Q * 16 + q16 * 4 + i;
                c0r[t2][i] = wsr[OFF_EC0 + b * HID + jg];
                c1r[t2][i] = wsr[OFF_EC1 + b * HID + jg];
            }
        }
    __syncthreads();

    float* accg = wsw + OFF_ACC;
    for (int st = 0; st < PRED; ++st) {
        uint2 hnew[8];
        // ================= layer 0 =================
        #pragma unroll 1
        for (int Q = 0; Q < 4; ++Q) {
            f32x4 acc[2][4];
            #pragma unroll
            for (int t = 0; t < 4; ++t) {
                float bb = bn0[wv * 256 + Q * 64 + t * 16 + m16];
                acc[0][t] = (f32x4){bb, bb, bb, bb};
                acc[1][t] = acc[0][t];
            }
            #pragma unroll
            for (int ks = 0; ks < 9; ++ks) {
                uint4 bw[4];
                #pragma unroll
                for (int t = 0; t < 4; ++t)
                    bw[t] = F0[(ks * 64 + wv * 16 + Q * 4 + t) * 64 + lane];
                #pragma unroll
                for (int mt = 0; mt < 2; ++mt) {
                    const _Float16* ap = (ks == 0)
                        ? &xlag[mt * 16 + m16][q16 * 8]
                        : &hA[0][mt * 16 + m16][(ks - 1) * 32 + q16 * 8];
                    half8 av = *(const half8*)ap;
                    #pragma unroll
                    for (int t = 0; t < 4; ++t)
                        acc[mt][t] = __builtin_amdgcn_mfma_f32_16x16x32_f16(
                            av, __builtin_bit_cast(half8, bw[t]), acc[mt][t], 0, 0, 0);
                }
            }
            #pragma unroll
            for (int mt = 0; mt < 2; ++mt) {
                #pragma unroll
                for (int t = 0; t < 4; ++t)
                    #pragma unroll
                    for (int rg = 0; rg < 4; ++rg)
                        scr[wv][q16 * 4 + rg][t * 16 + m16] = acc[mt][t][rg];
                __builtin_amdgcn_wave_barrier();
                int t2 = Q * 2 + mt;
                float hv[4];
                #pragma unroll
                for (int i = 0; i < 4; ++i) {
                    float4 g = *(const float4*)&scr[wv][m16][(q16 * 4 + i) * 4];
                    float c = sigm(g.y) * c0r[t2][i] + sigm(g.x) * ftanh(g.z);
                    c0r[t2][i] = c;
                    hv[i] = sigm(g.w) * ftanh(c);
                }
                __builtin_amdgcn_wave_barrier();
                hnew[t2] = make_uint2(packh2(hv[0], hv[1]), packh2(hv[2], hv[3]));
            }
        }
        __syncthreads();   // all L0 reads of hA[0]/xlag done
        #pragma unroll
        for (int Q = 0; Q < 4; ++Q)
            #pragma unroll
            for (int mt = 0; mt < 2; ++mt)
                *(uint2*)&hA[0][mt * 16 + m16][wv * 64 + Q * 16 + q16 * 4] = hnew[Q * 2 + mt];
        __syncthreads();   // hA[0] now h0(t)
        // ================= layer 1 =================
        #pragma unroll 1
        for (int Q = 0; Q < 4; ++Q) {
            f32x4 acc[2][4];
            #pragma unroll
            for (int t = 0; t < 4; ++t) {
                float bb = bn1[wv * 256 + Q * 64 + t * 16 + m16];
                acc[0][t] = (f32x4){bb, bb, bb, bb};
                acc[1][t] = acc[0][t];
            }
            #pragma unroll
            for (int ks = 0; ks < 16; ++ks) {
                uint4 bw[4];
                #pragma unroll
                for (int t = 0; t < 4; ++t)
                    bw[t] = F1[(ks * 64 + wv * 16 + Q * 4 + t) * 64 + lane];
                #pragma unroll
                for (int mt = 0; mt < 2; ++mt) {
                    const _Float16* ap = (ks < 8)
                        ? &hA[0][mt * 16 + m16][ks * 32 + q16 * 8]
                        : &hA[1][mt * 16 + m16][(ks - 8) * 32 + q16 * 8];
                    half8 av = *(const half8*)ap;
                    #pragma unroll
                    for (int t = 0; t < 4; ++t)
                        acc[mt][t] = __builtin_amdgcn_mfma_f32_16x16x32_f16(
                            av, __builtin_bit_cast(half8, bw[t]), acc[mt][t], 0, 0, 0);
                }
            }
            #pragma unroll
            for (int mt = 0; mt < 2; ++mt) {
                #pragma unroll
                for (int t = 0; t < 4; ++t)
                    #pragma unroll
                    for (int rg = 0; rg < 4; ++rg)
                        scr[wv][q16 * 4 + rg][t * 16 + m16] = acc[mt][t][rg];
                __builtin_amdgcn_wave_barrier();
                int t2 = Q * 2 + mt;
                float hv[4];
                #pragma unroll
                for (int i = 0; i < 4; ++i) {
                    float4 g = *(const float4*)&scr[wv][m16][(q16 * 4 + i) * 4];
                    float c = sigm(g.y) * c1r[t2][i] + sigm(g.x) * ftanh(g.z);
                    c1r[t2][i] = c;
                    hv[i] = sigm(g.w) * ftanh(c);
                }
                __builtin_amdgcn_wave_barrier();
                hnew[t2] = make_uint2(packh2(hv[0], hv[1]), packh2(hv[2], hv[3]));
            }
        }
        __syncthreads();   // all L1 reads of hA done
        #pragma unroll
        for (int Q = 0; Q < 4; ++Q)
            #pragma unroll
            for (int mt = 0; mt < 2; ++mt)
                *(uint2*)&hA[1][mt * 16 + m16][wv * 64 + Q * 16 + q16 * 4] = hnew[Q * 2 + mt];
        __syncthreads();   // hA[1] now h1(t)
        // ================= mu / sigma / sample =================
        #pragma unroll 1
        for (int it = 0; it < 8; ++it) {
            int rr = wv + it * 4;
            uint2 hu = *(const uint2*)&hA[1][rr][lane * 4];
            h2_t p0 = __builtin_bit_cast(h2_t, hu.x);
            h2_t p1 = __builtin_bit_cast(h2_t, hu.y);
            float4 wm = *(const float4*)&w_mu[lane * 4];
            float4 wsg = *(const float4*)&w_sigma[lane * 4];
            float h0f = (float)p0.x, h1f = (float)p0.y, h2f = (float)p1.x, h3f = (float)p1.y;
            float sm = h0f * wm.x + h1f * wm.y + h2f * wm.z + h3f * wm.w;
            float ss = h0f * wsg.x + h1f * wsg.y + h2f * wsg.z + h3f * wsg.w;
            #pragma unroll
            for (int off = 32; off > 0; off >>= 1) {
                sm += __shfl_down(sm, off, 64);
                ss += __shfl_down(ss, off, 64);
            }
            if (lane == 0) {
                float mu = sm + b_mu[0];
                float sg = softplus(ss + b_sigma[0]);
                int gr = gr0 + rr;
                float smp = fmaf(sg, eps[st * GROWS + gr], mu);
                atomicAdd(&accg[(gr / NS) * PRED + st], smp);
                #pragma unroll
                for (int f = NLAG - 1; f >= 1; --f) xlag[rr][f] = xlag[rr][f - 1];
                xlag[rr][0] = (_Float16)smp;
            }
        }
        __syncthreads();   // xlag(t+1) visible
    }
}

// ---------------- kernel 5: finalize ----------------
__global__ __launch_bounds__(256) void finalize_kernel(const float* __restrict__ ws,
                                                       float* __restrict__ out) {
    int i = blockIdx.x * blockDim.x + threadIdx.x;
    if (i < BATCH * PRED) {
        int b = i / PRED;
        out[i] = ws[OFF_ACC + i] * (1.0f / NS) * ws[OFF_SCALE + b] + ws[OFF_LOC + b];
    }
}

// ---------------- launch ----------------
extern "C" void kernel_launch(void* const* d_in, const int* in_sizes, int n_in,
                              void* d_out, int out_size, void* d_ws, size_t ws_size,
                              hipStream_t stream) {
    const float* targets = (const float*)d_in[0];
    const float* w_ih0 = (const float*)d_in[1];
    const float* w_hh0 = (const float*)d_in[2];
    const float* b_ih0 = (const float*)d_in[3];
    const float* b_hh0 = (const float*)d_in[4];
    const float* w_ih1 = (const float*)d_in[5];
    const float* w_hh1 = (const float*)d_in[6];
    const float* b_ih1 = (const float*)d_in[7];
    const float* b_hh1 = (const float*)d_in[8];
    const float* w_mu = (const float*)d_in[9];
    const float* b_mu = (const float*)d_in[10];
    const float* w_sigma = (const float*)d_in[11];
    const float* b_sigma = (const float*)d_in[12];
    const float* eps = (const float*)d_in[13];
    float* ws = (float*)d_ws;
    float* out = (float*)d_out;

    hipLaunchKernelGGL(prep_weights, dim3(1024), dim3(256), 0, stream,
                       w_ih0, w_hh0, b_ih0, b_hh0, w_ih1, w_hh1, b_ih1, b_hh1, ws);
    hipLaunchKernelGGL(prep_norm, dim3(BATCH), dim3(256), 0, stream, targets, ws);
    for (int c = 0; c < WIN / TCHUNK; ++c) {
        hipLaunchKernelGGL(enc0_kernel, dim3(128), dim3(1024), 0, stream, ws, c * TCHUNK);
        hipLaunchKernelGGL(enc1_kernel, dim3(128), dim3(1024), 0, stream, ws, c * TCHUNK);
    }
    hipLaunchKernelGGL(decoder_kernel, dim3(GROWS / RDEC), dim3(256), 0, stream,
                       ws, w_mu, b_mu, w_sigma, b_sigma, eps, ws);
    hipLaunchKernelGGL(finalize_kernel, dim3((BATCH * PRED + 255) / 256), dim3(256), 0,
                       stream, ws, out);
}

// Round 9
// 8739.245 us; speedup vs baseline: 1.3536x; 1.3536x over previous
//
#include <hip/hip_runtime.h>
#include <math.h>

// ---------------- problem constants ----------------
#define BATCH 256
#define TLEN  519          // W + MAXLAG
#define WIN   512
#define HID   256
#define PRED  24
#define NS    100
#define NLAG  7
#define GROWS (BATCH * NS) // 25600 decoder rows
#define TCHUNK 128         // encoder time chunk (4 chunks of 128)

// ---------------- workspace layout (float/uint offsets) ----------------
#define OFF_SCALED 0
#define OFF_LOC    132864
#define OFF_SCALE  133120
#define OFF_WIH0   133376   // fp32 [f][j][q], f<7  (encoder lag weights)
#define OFF_WHH0H  140544   // half2 [p][j][q], p<128 (encoder L0 recurrent)
#define OFF_WCAT1H 271616   // half2 [p][j][q], p<256 (p>=128 = w_hh1, enc1 recurrent)
#define OFF_B0     533760   // fp32 combined b_ih0+b_hh0, [j][q]
#define OFF_B1     534784
#define OFF_BN0    535808   // fp32 bias by MFMA col n (layer0)
#define OFF_BN1    536832
#define OFF_F0     537856   // fp16 B-fragments layer0: 9 ks x 64 nt x 64 lane x 8
#define OFF_F1     685312   // fp16 B-fragments layer1: 16 ks x 64 nt x 64 lane x 8
#define OFF_EH0    947456   // encoder states fp32 [b][j] (chunk-carried)
#define OFF_EC0    1012992
#define OFF_EH1    1078528
#define OFF_EC1    1144064
#define OFF_ACC    1209600  // sample accumulators [b][p]
#define OFF_TRAJ   1215744  // fp16 h0 trajectory [b][tl<128][256] = 16.8 MB
#define WS_FLOATS  5410048  // 21.6 MB

// ---------------- helpers ----------------
typedef _Float16 h2_t  __attribute__((ext_vector_type(2)));
typedef _Float16 half8 __attribute__((ext_vector_type(8)));
typedef float    f32x4 __attribute__((ext_vector_type(4)));

__device__ __forceinline__ float sigm(float x) { return 1.0f / (1.0f + __expf(-x)); }
__device__ __forceinline__ float ftanh(float x) {
    float e = __expf(2.0f * x);
    return 1.0f - 2.0f / (e + 1.0f);
}
__device__ __forceinline__ float softplus(float x) {
    return (x > 15.0f) ? x : log1pf(__expf(x));
}
__device__ __forceinline__ void fma4(float4& a, const float4 w, const float x) {
    a.x = fmaf(w.x, x, a.x);
    a.y = fmaf(w.y, x, a.y);
    a.z = fmaf(w.z, x, a.z);
    a.w = fmaf(w.w, x, a.w);
}
__device__ __forceinline__ float dot2(unsigned int h, unsigned int w, float acc) {
    return __builtin_amdgcn_fdot2(__builtin_bit_cast(h2_t, h),
                                  __builtin_bit_cast(h2_t, w), acc, false);
}
__device__ __forceinline__ void dot2x4(float4& a, const unsigned int h, const uint4 w) {
    a.x = dot2(h, w.x, a.x);
    a.y = dot2(h, w.y, a.y);
    a.z = dot2(h, w.z, a.z);
    a.w = dot2(h, w.w, a.w);
}
__device__ __forceinline__ unsigned int packh2(float a, float b) {
    h2_t h;
    h.x = (_Float16)a;
    h.y = (_Float16)b;
    return __builtin_bit_cast(unsigned int, h);
}
__device__ __forceinline__ unsigned short hbits(float v) {
    return __builtin_bit_cast(unsigned short, (_Float16)v);
}

// ---------------- kernel 1: repack weights ----------------
__global__ __launch_bounds__(256) void prep_weights(
    const float* __restrict__ w_ih0, const float* __restrict__ w_hh0,
    const float* __restrict__ b_ih0, const float* __restrict__ b_hh0,
    const float* __restrict__ w_ih1, const float* __restrict__ w_hh1,
    const float* __restrict__ b_ih1, const float* __restrict__ b_hh1,
    float* __restrict__ ws) {
    int id = blockIdx.x * blockDim.x + threadIdx.x;   // grid covers 262144
    unsigned int* wsu = (unsigned int*)ws;
    // ---- encoder layouts ----
    {
        int g4 = id & 1023;
        int jj = g4 >> 2, q = g4 & 3;
        int grow = q * HID + jj;
        int p = id >> 10;
        int k0 = 2 * p;
        float v0, v1;
        if (k0 < 256) { v0 = w_ih1[grow * HID + k0];       v1 = w_ih1[grow * HID + k0 + 1]; }
        else          { v0 = w_hh1[grow * HID + k0 - 256]; v1 = w_hh1[grow * HID + k0 - 255]; }
        wsu[OFF_WCAT1H + id] = packh2(v0, v1);
        if (id < 131072) {
            wsu[OFF_WHH0H + id] = packh2(w_hh0[grow * HID + 2 * p], w_hh0[grow * HID + 2 * p + 1]);
        }
        if (id < 7168) {
            int f = id >> 10;
            ws[OFF_WIH0 + id] = w_ih0[grow * NLAG + f];
        }
        if (id < 1024) {
            ws[OFF_B0 + id] = b_ih0[grow] + b_hh0[grow];
            ws[OFF_B1 + id] = b_ih1[grow] + b_hh1[grow];
        }
    }
    // ---- decoder/enc1 biases by MFMA col ----
    if (id < 2048) {
        int n = id & 1023;
        int w = n >> 8, u = (n >> 2) & 63, q = n & 3;
        int grow = q * HID + w * 64 + u;
        if (id < 1024) ws[OFF_BN0 + n] = b_ih0[grow] + b_hh0[grow];
        else           ws[OFF_BN1 + n] = b_ih1[grow] + b_hh1[grow];
    }
    // ---- F0 fragments: 9 ks (ks0 = lag block) ----
    if (id < 36864) {
        int ks = id / 4096, rem = id % 4096, nt = rem >> 6, l = rem & 63;
        int n = nt * 16 + (l & 15);
        int w = n >> 8, u = (n >> 2) & 63, q = n & 3;
        int grow = q * HID + w * 64 + u;
        int kbase = (l >> 4) * 8;
        unsigned short h8[8];
        #pragma unroll
        for (int i = 0; i < 8; ++i) {
            float v;
            if (ks == 0) { int k = kbase + i; v = (k < NLAG) ? w_ih0[grow * NLAG + k] : 0.0f; }
            else         { int kk = (ks - 1) * 32 + kbase + i; v = w_hh0[grow * HID + kk]; }
            h8[i] = hbits(v);
        }
        uint4 o;
        o.x = (unsigned int)h8[0] | ((unsigned int)h8[1] << 16);
        o.y = (unsigned int)h8[2] | ((unsigned int)h8[3] << 16);
        o.z = (unsigned int)h8[4] | ((unsigned int)h8[5] << 16);
        o.w = (unsigned int)h8[6] | ((unsigned int)h8[7] << 16);
        ((uint4*)(ws + OFF_F0))[id] = o;
    }
    // ---- F1 fragments: 16 ks (ks<8 = w_ih1, used by enc1 MFMA + decoder) ----
    if (id < 65536) {
        int ks = id >> 12, rem = id & 4095, nt = rem >> 6, l = rem & 63;
        int n = nt * 16 + (l & 15);
        int w = n >> 8, u = (n >> 2) & 63, q = n & 3;
        int grow = q * HID + w * 64 + u;
        int kbase = (l >> 4) * 8;
        unsigned short h8[8];
        #pragma unroll
        for (int i = 0; i < 8; ++i) {
            int kk = ks * 32 + kbase + i;
            float v = (kk < 256) ? w_ih1[grow * HID + kk] : w_hh1[grow * HID + kk - 256];
            h8[i] = hbits(v);
        }
        uint4 o;
        o.x = (unsigned int)h8[0] | ((unsigned int)h8[1] << 16);
        o.y = (unsigned int)h8[2] | ((unsigned int)h8[3] << 16);
        o.z = (unsigned int)h8[4] | ((unsigned int)h8[5] << 16);
        o.w = (unsigned int)h8[6] | ((unsigned int)h8[7] << 16);
        ((uint4*)(ws + OFF_F1))[id] = o;
    }
}

// ---------------- kernel 2: normalize + zero accumulators ----------------
__global__ __launch_bounds__(256) void prep_norm(const float* __restrict__ x,
                                                 float* __restrict__ ws) {
    const int b = blockIdx.x, j = threadIdx.x;
    const float* row = x + b * TLEN;
    float s = 0.0f, s2 = 0.0f;
    for (int t = j; t < WIN; t += 256) {
        float v = row[NLAG + t];
        s += v;
        s2 = fmaf(v, v, s2);
    }
    #pragma unroll
    for (int off = 32; off > 0; off >>= 1) {
        s  += __shfl_down(s, off, 64);
        s2 += __shfl_down(s2, off, 64);
    }
    __shared__ float rs[4], rs2[4];
    __shared__ float sh_loc, sh_scale;
    int wave = j >> 6, lane = j & 63;
    if (lane == 0) { rs[wave] = s; rs2[wave] = s2; }
    __syncthreads();
    if (j == 0) {
        float S = rs[0] + rs[1] + rs[2] + rs[3];
        float S2 = rs2[0] + rs2[1] + rs2[2] + rs2[3];
        float mean = S * (1.0f / WIN);
        float var = S2 * (1.0f / WIN) - mean * mean;
        float sd = sqrtf(fmaxf(var, 0.0f));
        if (sd < 1e-10f) sd = 1.0f;
        sh_loc = mean; sh_scale = sd;
        ws[OFF_LOC + b] = mean;
        ws[OFF_SCALE + b] = sd;
    }
    __syncthreads();
    float loc = sh_loc, inv = 1.0f / sh_scale;
    for (int t = j; t < TLEN; t += 256) {
        ws[OFF_SCALED + b * TLEN + t] = (row[t] - loc) * inv;
    }
    if (j < PRED) ws[OFF_ACC + b * PRED + j] = 0.0f;
}

// ---------------- kernel 3a: encoder L0 phase (one 128-step chunk) ----------------
// 128 blocks x 1024 threads, 2 rows/block, 4-way in-block k-split over w_hh0
// ONLY (512 KB/step). Writes the h0 trajectory (fp16) for enc1's A-operand.
__global__ __launch_bounds__(1024) void enc0_kernel(float* __restrict__ ws, int tc) {
    const int tid = threadIdx.x;
    const int j  = tid & 255;      // unit
    const int kq = tid >> 8;       // k-quarter (0..3)
    const int bb = blockIdx.x;     // 0..127
    __shared__ unsigned int h0p[2][128];
    __shared__ float4 pgs[2][4][256];
    __shared__ float4 wlag[NLAG * 256];   // lag weights fp32 (28 KB)
    __shared__ float xs[2][NLAG];
    float c0[2] = {0.0f, 0.0f};

    for (int i = tid; i < NLAG * 256; i += 1024)
        wlag[i] = ((const float4*)(ws + OFF_WIH0))[i];
    const uint4* W0 = (const uint4*)((const unsigned int*)ws + OFF_WHH0H);
    float4 bv0 = {0, 0, 0, 0};
    if (kq == 0) {
        bv0 = ((const float4*)(ws + OFF_B0))[j];
        #pragma unroll
        for (int r = 0; r < 2; ++r) {
            int b = bb * 2 + r;
            if (tc == 0) {
                c0[r] = 0.0f;
                ((_Float16*)&h0p[r][0])[j] = (_Float16)0.0f;
            } else {
                c0[r] = ws[OFF_EC0 + b * HID + j];
                ((_Float16*)&h0p[r][0])[j] = (_Float16)ws[OFF_EH0 + b * HID + j];
            }
        }
    }
    const float* sc0 = ws + OFF_SCALED + (bb * 2 + 0) * TLEN;
    const float* sc1 = ws + OFF_SCALED + (bb * 2 + 1) * TLEN;
    _Float16* traj = (_Float16*)(ws + OFF_TRAJ);
    __syncthreads();

    for (int tl = 0; tl < TCHUNK; ++tl) {
        int t = tc + tl;
        if (tid < 2 * NLAG) {
            int r = tid / NLAG, f = tid % NLAG;
            xs[r][f] = (r ? sc1 : sc0)[t + 6 - f];
        }
        // L0 partials: 32 k-pairs per quarter
        {
            float4 a0 = {0, 0, 0, 0}, a1 = {0, 0, 0, 0};
            const uint4* Wp = W0 + (kq * 32) * 256 + j;
            const unsigned int* hp0 = &h0p[0][kq * 32];
            const unsigned int* hp1 = &h0p[1][kq * 32];
            #pragma unroll 4
            for (int p = 0; p < 32; ++p) {
                uint4 w = Wp[p * 256];
                dot2x4(a0, hp0[p], w);
                dot2x4(a1, hp1[p], w);
            }
            pgs[0][kq][j] = a0;
            pgs[1][kq][j] = a1;
        }
        __syncthreads();   // pgs + xs ready; L0 reads of h0p done
        if (kq == 0) {
            #pragma unroll
            for (int r = 0; r < 2; ++r) {
                float4 a = bv0;
                #pragma unroll
                for (int f = 0; f < NLAG; ++f) fma4(a, wlag[f * 256 + j], xs[r][f]);
                #pragma unroll
                for (int h = 0; h < 4; ++h) {
                    float4 p = pgs[r][h][j];
                    a.x += p.x; a.y += p.y; a.z += p.z; a.w += p.w;
                }
                c0[r] = sigm(a.y) * c0[r] + sigm(a.x) * ftanh(a.z);
                _Float16 hh = (_Float16)(sigm(a.w) * ftanh(c0[r]));
                ((_Float16*)&h0p[r][0])[j] = hh;
                traj[((bb * 2 + r) * TCHUNK + tl) * HID + j] = hh;
            }
        }
        __syncthreads();   // h0p(t) visible
    }
    if (kq == 0) {
        #pragma unroll
        for (int r = 0; r < 2; ++r) {
            int b = bb * 2 + r;
            ws[OFF_EH0 + b * HID + j] = (float)((_Float16*)&h0p[r][0])[j];
            ws[OFF_EC0 + b * HID + j] = c0[r];
        }
    }
}

// ---------------- kernel 3b: encoder L1 phase (one 128-step chunk) ----------------
// Per 8-step group: one MFMA batch (M=16 = 2 rows x 8 steps) computes
// P = h0 @ w_ih1^T + bias into LDS via the F1 fragments (ks<8), amortizing
// w_ih1's 512 KB over 8 steps; then 8 sub-steps stream only w_hh1.
__global__ __launch_bounds__(1024) void enc1_kernel(float* __restrict__ ws, int tc) {
    const int tid = threadIdx.x;
    const int lane = tid & 63, wv = tid >> 6;   // 16 waves
    const int j  = tid & 255;
    const int kq = tid >> 8;
    const int bb = blockIdx.x;
    const int m16 = lane & 15, q16 = lane >> 4;
    __shared__ float P[16][1028];          // [m = r*8+ss][gate col n], 65.8 KB
    __shared__ float4 pgs[2][4][256];      // 32 KB
    __shared__ unsigned int h1p[2][128];
    float c1[2] = {0.0f, 0.0f};

    const uint4* F1 = (const uint4*)(ws + OFF_F1);
    const uint4* W1 = (const uint4*)((const unsigned int*)ws + OFF_WCAT1H);
    const float* bn1 = ws + OFF_BN1;
    const _Float16* traj = (const _Float16*)(ws + OFF_TRAJ);

    if (kq == 0) {
        #pragma unroll
        for (int r = 0; r < 2; ++r) {
            int b = bb * 2 + r;
            if (tc == 0) {
                c1[r] = 0.0f;
                ((_Float16*)&h1p[r][0])[j] = (_Float16)0.0f;
            } else {
                c1[r] = ws[OFF_EC1 + b * HID + j];
                ((_Float16*)&h1p[r][0])[j] = (_Float16)ws[OFF_EH1 + b * HID + j];
            }
        }
    }
    __syncthreads();

    for (int g8 = 0; g8 < TCHUNK / 8; ++g8) {
        // ---- MFMA batch: P[m][n] = bias + sum_k h0[m][k] * w_ih1[n][k] ----
        {
            const int ntb = wv * 4;   // this wave's 4 n-tiles
            f32x4 acc[4];
            #pragma unroll
            for (int qq = 0; qq < 4; ++qq) {
                float b = bn1[(ntb + qq) * 16 + m16];
                acc[qq] = (f32x4){b, b, b, b};
            }
            #pragma unroll
            for (int ks = 0; ks < 8; ++ks) {
                const _Float16* ap = traj +
                    (((bb * 2 + (m16 >> 3)) * TCHUNK) + g8 * 8 + (m16 & 7)) * HID +
                    q16 * 8 + ks * 32;
                half8 av = *(const half8*)ap;
                #pragma unroll
                for (int qq = 0; qq < 4; ++qq) {
                    uint4 bw = F1[(ks * 64 + ntb + qq) * 64 + lane];
                    acc[qq] = __builtin_amdgcn_mfma_f32_16x16x32_f16(
                        av, __builtin_bit_cast(half8, bw), acc[qq], 0, 0, 0);
                }
            }
            #pragma unroll
            for (int qq = 0; qq < 4; ++qq)
                #pragma unroll
                for (int rg = 0; rg < 4; ++rg)
                    P[q16 * 4 + rg][(ntb + qq) * 16 + m16] = acc[qq][rg];
        }
        __syncthreads();   // P ready; also guards P overwrite vs prior reads
        // ---- 8 sequential sub-steps: recurrent w_hh1 only ----
        for (int ss = 0; ss < 8; ++ss) {
            {
                float4 a0 = {0, 0, 0, 0}, a1 = {0, 0, 0, 0};
                const uint4* Wp = W1 + (128 + kq * 32) * 256 + j;
                const unsigned int* hp0 = &h1p[0][kq * 32];
                const unsigned int* hp1 = &h1p[1][kq * 32];
                #pragma unroll 4
                for (int p = 0; p < 32; ++p) {
                    uint4 w = Wp[p * 256];
                    dot2x4(a0, hp0[p], w);
                    dot2x4(a1, hp1[p], w);
                }
                pgs[0][kq][j] = a0;
                pgs[1][kq][j] = a1;
            }
            __syncthreads();   // pgs ready; reads of h1p done
            if (kq == 0) {
                #pragma unroll
                for (int r = 0; r < 2; ++r) {
                    int m = r * 8 + ss;
                    float4 a = *(const float4*)&P[m][j * 4];
                    #pragma unroll
                    for (int h = 0; h < 4; ++h) {
                        float4 p = pgs[r][h][j];
                        a.x += p.x; a.y += p.y; a.z += p.z; a.w += p.w;
                    }
                    c1[r] = sigm(a.y) * c1[r] + sigm(a.x) * ftanh(a.z);
                    ((_Float16*)&h1p[r][0])[j] = (_Float16)(sigm(a.w) * ftanh(c1[r]));
                }
            }
            __syncthreads();   // h1p(t) visible
        }
    }
    if (kq == 0) {
        #pragma unroll
        for (int r = 0; r < 2; ++r) {
            int b = bb * 2 + r;
            ws[OFF_EH1 + b * HID + j] = (float)((_Float16*)&h1p[r][0])[j];
            ws[OFF_EC1 + b * HID + j] = c1[r];
        }
    }
}

// ---------------- kernel 4: MFMA decoder (r4/r7-verified, RDEC=32, (256,2)) ----------------
// VGPR 128, no spill. DO NOT raise min-occupancy: (256,3) forced VGPR 84 ->
// spill -> 8.4 GB scratch writebacks -> 6.6 ms (r8). (256,2) is the ceiling.
#define RDEC 32
__global__ __launch_bounds__(256, 2) void decoder_kernel(
    const float* __restrict__ wsr,
    const float* __restrict__ w_mu, const float* __restrict__ b_mu,
    const float* __restrict__ w_sigma, const float* __restrict__ b_sigma,
    const float* __restrict__ eps, float* __restrict__ wsw) {
    const int j = threadIdx.x, lane = j & 63, wv = j >> 6;
    const int gr0 = blockIdx.x * RDEC;
    const int m16 = lane & 15, q16 = lane >> 4;
    __shared__ _Float16 hA[2][RDEC][264];   // [layer][row][unit], pad to 264
    __shared__ _Float16 xlag[RDEC][32];     // lag A-tile (k 0..6 live, rest 0)
    __shared__ float scr[4][16][68];        // per-wave D transpose scratch

    const uint4* F0 = (const uint4*)(wsr + OFF_F0);
    const uint4* F1 = (const uint4*)(wsr + OFF_F1);
    const float* bn0 = wsr + OFF_BN0;
    const float* bn1 = wsr + OFF_BN1;

    float c0r[8][4], c1r[8][4];
    for (int r = 0; r < RDEC; ++r) {
        int b = (gr0 + r) / NS;
        hA[0][r][j] = (_Float16)wsr[OFF_EH0 + b * HID + j];
        hA[1][r][j] = (_Float16)wsr[OFF_EH1 + b * HID + j];
    }
    { int r = j >> 3, p = j & 7;
      hA[0][r][256 + p] = (_Float16)0.0f; hA[1][r][256 + p] = (_Float16)0.0f; }
    #pragma unroll
    for (int it = 0; it < 4; ++it) {
        int idx = j + 256 * it;
        int r = idx >> 5, k = idx & 31;
        int b = (gr0 + r) / NS;
        xlag[r][k] = (k < NLAG) ? (_Float16)wsr[OFF_SCALED + b * TLEN + WIN + 6 - k]
                                : (_Float16)0.0f;
    }
    #pragma unroll
    for (int Q = 0; Q < 4; ++Q)
        #pragma unroll
        for (int mt = 0; mt < 2; ++mt) {
            int t2 = Q * 2 + mt;
            int b = (gr0 + mt * 16 + m16) / NS;
            #pragma unroll
            for (int i = 0; i < 4; ++i) {
                int jg = wv * 64 + Q * 16 + q16 * 4 + i;
                c0r[t2][i] = wsr[OFF_EC0 + b * HID + jg];
                c1r[t2][i] = wsr[OFF_EC1 + b * HID + jg];
            }
        }
    __syncthreads();

    float* accg = wsw + OFF_ACC;
    for (int st = 0; st < PRED; ++st) {
        uint2 hnew[8];
        // ================= layer 0 =================
        #pragma unroll 1
        for (int Q = 0; Q < 4; ++Q) {
            f32x4 acc[2][4];
            #pragma unroll
            for (int t = 0; t < 4; ++t) {
                float bb = bn0[wv * 256 + Q * 64 + t * 16 + m16];
                acc[0][t] = (f32x4){bb, bb, bb, bb};
                acc[1][t] = acc[0][t];
            }
            #pragma unroll
            for (int ks = 0; ks < 9; ++ks) {
                uint4 bw[4];
                #pragma unroll
                for (int t = 0; t < 4; ++t)
                    bw[t] = F0[(ks * 64 + wv * 16 + Q * 4 + t) * 64 + lane];
                #pragma unroll
                for (int mt = 0; mt < 2; ++mt) {
                    const _Float16* ap = (ks == 0)
                        ? &xlag[mt * 16 + m16][q16 * 8]
                        : &hA[0][mt * 16 + m16][(ks - 1) * 32 + q16 * 8];
                    half8 av = *(const half8*)ap;
                    #pragma unroll
                    for (int t = 0; t < 4; ++t)
                        acc[mt][t] = __builtin_amdgcn_mfma_f32_16x16x32_f16(
                            av, __builtin_bit_cast(half8, bw[t]), acc[mt][t], 0, 0, 0);
                }
            }
            #pragma unroll
            for (int mt = 0; mt < 2; ++mt) {
                #pragma unroll
                for (int t = 0; t < 4; ++t)
                    #pragma unroll
                    for (int rg = 0; rg < 4; ++rg)
                        scr[wv][q16 * 4 + rg][t * 16 + m16] = acc[mt][t][rg];
                __builtin_amdgcn_wave_barrier();
                int t2 = Q * 2 + mt;
                float hv[4];
                #pragma unroll
                for (int i = 0; i < 4; ++i) {
                    float4 g = *(const float4*)&scr[wv][m16][(q16 * 4 + i) * 4];
                    float c = sigm(g.y) * c0r[t2][i] + sigm(g.x) * ftanh(g.z);
                    c0r[t2][i] = c;
                    hv[i] = sigm(g.w) * ftanh(c);
                }
                __builtin_amdgcn_wave_barrier();
                hnew[t2] = make_uint2(packh2(hv[0], hv[1]), packh2(hv[2], hv[3]));
            }
        }
        __syncthreads();   // all L0 reads of hA[0]/xlag done
        #pragma unroll
        for (int Q = 0; Q < 4; ++Q)
            #pragma unroll
            for (int mt = 0; mt < 2; ++mt)
                *(uint2*)&hA[0][mt * 16 + m16][wv * 64 + Q * 16 + q16 * 4] = hnew[Q * 2 + mt];
        __syncthreads();   // hA[0] now h0(t)
        // ================= layer 1 =================
        #pragma unroll 1
        for (int Q = 0; Q < 4; ++Q) {
            f32x4 acc[2][4];
            #pragma unroll
            for (int t = 0; t < 4; ++t) {
                float bb = bn1[wv * 256 + Q * 64 + t * 16 + m16];
                acc[0][t] = (f32x4){bb, bb, bb, bb};
                acc[1][t] = acc[0][t];
            }
            #pragma unroll
            for (int ks = 0; ks < 16; ++ks) {
                uint4 bw[4];
                #pragma unroll
                for (int t = 0; t < 4; ++t)
                    bw[t] = F1[(ks * 64 + wv * 16 + Q * 4 + t) * 64 + lane];
                #pragma unroll
                for (int mt = 0; mt < 2; ++mt) {
                    const _Float16* ap = (ks < 8)
                        ? &hA[0][mt * 16 + m16][ks * 32 + q16 * 8]
                        : &hA[1][mt * 16 + m16][(ks - 8) * 32 + q16 * 8];
                    half8 av = *(const half8*)ap;
                    #pragma unroll
                    for (int t = 0; t < 4; ++t)
                        acc[mt][t] = __builtin_amdgcn_mfma_f32_16x16x32_f16(
                            av, __builtin_bit_cast(half8, bw[t]), acc[mt][t], 0, 0, 0);
                }
            }
            #pragma unroll
            for (int mt = 0; mt < 2; ++mt) {
                #pragma unroll
                for (int t = 0; t < 4; ++t)
                    #pragma unroll
                    for (int rg = 0; rg < 4; ++rg)
                        scr[wv][q16 * 4 + rg][t * 16 + m16] = acc[mt][t][rg];
                __builtin_amdgcn_wave_barrier();
                int t2 = Q * 2 + mt;
                float hv[4];
                #pragma unroll
                for (int i = 0; i < 4; ++i) {
                    float4 g = *(const float4*)&scr[wv][m16][(q16 * 4 + i) * 4];
                    float c = sigm(g.y) * c1r[t2][i] + sigm(g.x) * ftanh(g.z);
                    c1r[t2][i] = c;
                    hv[i] = sigm(g.w) * ftanh(c);
                }
                __builtin_amdgcn_wave_barrier();
                hnew[t2] = make_uint2(packh2(hv[0], hv[1]), packh2(hv[2], hv[3]));
            }
        }
        __syncthreads();   // all L1 reads of hA done
        #pragma unroll
        for (int Q = 0; Q < 4; ++Q)
            #pragma unroll
            for (int mt = 0; mt < 2; ++mt)
                *(uint2*)&hA[1][mt * 16 + m16][wv * 64 + Q * 16 + q16 * 4] = hnew[Q * 2 + mt];
        __syncthreads();   // hA[1] now h1(t)
        // ================= mu / sigma / sample =================
        #pragma unroll 1
        for (int it = 0; it < 8; ++it) {
            int rr = wv + it * 4;
            uint2 hu = *(const uint2*)&hA[1][rr][lane * 4];
            h2_t p0 = __builtin_bit_cast(h2_t, hu.x);
            h2_t p1 = __builtin_bit_cast(h2_t, hu.y);
            float4 wm = *(const float4*)&w_mu[lane * 4];
            float4 wsg = *(const float4*)&w_sigma[lane * 4];
            float h0f = (float)p0.x, h1f = (float)p0.y, h2f = (float)p1.x, h3f = (float)p1.y;
            float sm = h0f * wm.x + h1f * wm.y + h2f * wm.z + h3f * wm.w;
            float ss = h0f * wsg.x + h1f * wsg.y + h2f * wsg.z + h3f * wsg.w;
            #pragma unroll
            for (int off = 32; off > 0; off >>= 1) {
                sm += __shfl_down(sm, off, 64);
                ss += __shfl_down(ss, off, 64);
            }
            if (lane == 0) {
                float mu = sm + b_mu[0];
                float sg = softplus(ss + b_sigma[0]);
                int gr = gr0 + rr;
                float smp = fmaf(sg, eps[st * GROWS + gr], mu);
                atomicAdd(&accg[(gr / NS) * PRED + st], smp);
                #pragma unroll
                for (int f = NLAG - 1; f >= 1; --f) xlag[rr][f] = xlag[rr][f - 1];
                xlag[rr][0] = (_Float16)smp;
            }
        }
        __syncthreads();   // xlag(t+1) visible
    }
}

// ---------------- kernel 5: finalize ----------------
__global__ __launch_bounds__(256) void finalize_kernel(const float* __restrict__ ws,
                                                       float* __restrict__ out) {
    int i = blockIdx.x * blockDim.x + threadIdx.x;
    if (i < BATCH * PRED) {
        int b = i / PRED;
        out[i] = ws[OFF_ACC + i] * (1.0f / NS) * ws[OFF_SCALE + b] + ws[OFF_LOC + b];
    }
}

// ---------------- launch ----------------
extern "C" void kernel_launch(void* const* d_in, const int* in_sizes, int n_in,
                              void* d_out, int out_size, void* d_ws, size_t ws_size,
                              hipStream_t stream) {
    const float* targets = (const float*)d_in[0];
    const float* w_ih0 = (const float*)d_in[1];
    const float* w_hh0 = (const float*)d_in[2];
    const float* b_ih0 = (const float*)d_in[3];
    const float* b_hh0 = (const float*)d_in[4];
    const float* w_ih1 = (const float*)d_in[5];
    const float* w_hh1 = (const float*)d_in[6];
    const float* b_ih1 = (const float*)d_in[7];
    const float* b_hh1 = (const float*)d_in[8];
    const float* w_mu = (const float*)d_in[9];
    const float* b_mu = (const float*)d_in[10];
    const float* w_sigma = (const float*)d_in[11];
    const float* b_sigma = (const float*)d_in[12];
    const float* eps = (const float*)d_in[13];
    float* ws = (float*)d_ws;
    float* out = (float*)d_out;

    hipLaunchKernelGGL(prep_weights, dim3(1024), dim3(256), 0, stream,
                       w_ih0, w_hh0, b_ih0, b_hh0, w_ih1, w_hh1, b_ih1, b_hh1, ws);
    hipLaunchKernelGGL(prep_norm, dim3(BATCH), dim3(256), 0, stream, targets, ws);
    for (int c = 0; c < WIN / TCHUNK; ++c) {
        hipLaunchKernelGGL(enc0_kernel, dim3(128), dim3(1024), 0, stream, ws, c * TCHUNK);
        hipLaunchKernelGGL(enc1_kernel, dim3(128), dim3(1024), 0, stream, ws, c * TCHUNK);
    }
    hipLaunchKernelGGL(decoder_kernel, dim3(GROWS / RDEC), dim3(256), 0, stream,
                       ws, w_mu, b_mu, w_sigma, b_sigma, eps, ws);
    hipLaunchKernelGGL(finalize_kernel, dim3((BATCH * PRED + 255) / 256), dim3(256), 0,
                       stream, ws, out);
}

// Round 10
// 6653.558 us; speedup vs baseline: 1.7779x; 1.3135x over previous
//
#include <hip/hip_runtime.h>
#include <math.h>

// ---------------- problem constants ----------------
#define BATCH 256
#define TLEN  519          // W + MAXLAG
#define WIN   512
#define HID   256
#define PRED  24
#define NS    100
#define NLAG  7
#define GROWS (BATCH * NS) // 25600 decoder rows
#define TCHUNK 64          // encoder time chunk (8 chunks; double-buffered traj)
#define NCHUNK (WIN / TCHUNK)

// ---------------- workspace layout (float/uint offsets) ----------------
#define OFF_SCALED 0
#define OFF_LOC    132864
#define OFF_SCALE  133120
#define OFF_WIH0   133376   // fp32 [f][j][q], f<7  (encoder lag weights)
#define OFF_WHH0H  140544   // half2 [p][j][q], p<128 (encoder L0 recurrent)
#define OFF_WCAT1H 271616   // half2 [p][j][q], p<256 (p>=128 = w_hh1, enc1 recurrent)
#define OFF_B0     533760   // fp32 combined b_ih0+b_hh0, [j][q]
#define OFF_B1     534784
#define OFF_BN0    535808   // fp32 bias by MFMA col n (layer0)
#define OFF_BN1    536832
#define OFF_F0     537856   // fp16 B-fragments layer0: 9 ks x 64 nt x 64 lane x 8
#define OFF_F1     685312   // fp16 B-fragments layer1: 16 ks x 64 nt x 64 lane x 8
#define OFF_EH0    947456   // encoder states fp32 [b][j] (chunk-carried)
#define OFF_EC0    1012992
#define OFF_EH1    1078528
#define OFF_EC1    1144064
#define OFF_ACC    1209600  // sample accumulators [b][p]
#define OFF_TRAJ   1215744  // fp16 h0 trajectory, 2 buffers x [b][tl<64][256] = 16.8 MB
#define TRAJ_HALVES (BATCH * TCHUNK * HID)   // per buffer: 4,194,304 halves
#define WS_FLOATS  5410048  // 21.6 MB (same footprint as r9)

// ---------------- helpers ----------------
typedef _Float16 h2_t  __attribute__((ext_vector_type(2)));
typedef _Float16 half8 __attribute__((ext_vector_type(8)));
typedef float    f32x4 __attribute__((ext_vector_type(4)));

__device__ __forceinline__ float sigm(float x) { return 1.0f / (1.0f + __expf(-x)); }
__device__ __forceinline__ float ftanh(float x) {
    float e = __expf(2.0f * x);
    return 1.0f - 2.0f / (e + 1.0f);
}
__device__ __forceinline__ float softplus(float x) {
    return (x > 15.0f) ? x : log1pf(__expf(x));
}
__device__ __forceinline__ void fma4(float4& a, const float4 w, const float x) {
    a.x = fmaf(w.x, x, a.x);
    a.y = fmaf(w.y, x, a.y);
    a.z = fmaf(w.z, x, a.z);
    a.w = fmaf(w.w, x, a.w);
}
__device__ __forceinline__ float dot2(unsigned int h, unsigned int w, float acc) {
    return __builtin_amdgcn_fdot2(__builtin_bit_cast(h2_t, h),
                                  __builtin_bit_cast(h2_t, w), acc, false);
}
__device__ __forceinline__ void dot2x4(float4& a, const unsigned int h, const uint4 w) {
    a.x = dot2(h, w.x, a.x);
    a.y = dot2(h, w.y, a.y);
    a.z = dot2(h, w.z, a.z);
    a.w = dot2(h, w.w, a.w);
}
__device__ __forceinline__ unsigned int packh2(float a, float b) {
    h2_t h;
    h.x = (_Float16)a;
    h.y = (_Float16)b;
    return __builtin_bit_cast(unsigned int, h);
}
__device__ __forceinline__ unsigned short hbits(float v) {
    return __builtin_bit_cast(unsigned short, (_Float16)v);
}

// ---------------- kernel 1: repack weights ----------------
__global__ __launch_bounds__(256) void prep_weights(
    const float* __restrict__ w_ih0, const float* __restrict__ w_hh0,
    const float* __restrict__ b_ih0, const float* __restrict__ b_hh0,
    const float* __restrict__ w_ih1, const float* __restrict__ w_hh1,
    const float* __restrict__ b_ih1, const float* __restrict__ b_hh1,
    float* __restrict__ ws) {
    int id = blockIdx.x * blockDim.x + threadIdx.x;   // grid covers 262144
    unsigned int* wsu = (unsigned int*)ws;
    // ---- encoder layouts ----
    {
        int g4 = id & 1023;
        int jj = g4 >> 2, q = g4 & 3;
        int grow = q * HID + jj;
        int p = id >> 10;
        int k0 = 2 * p;
        float v0, v1;
        if (k0 < 256) { v0 = w_ih1[grow * HID + k0];       v1 = w_ih1[grow * HID + k0 + 1]; }
        else          { v0 = w_hh1[grow * HID + k0 - 256]; v1 = w_hh1[grow * HID + k0 - 255]; }
        wsu[OFF_WCAT1H + id] = packh2(v0, v1);
        if (id < 131072) {
            wsu[OFF_WHH0H + id] = packh2(w_hh0[grow * HID + 2 * p], w_hh0[grow * HID + 2 * p + 1]);
        }
        if (id < 7168) {
            int f = id >> 10;
            ws[OFF_WIH0 + id] = w_ih0[grow * NLAG + f];
        }
        if (id < 1024) {
            ws[OFF_B0 + id] = b_ih0[grow] + b_hh0[grow];
            ws[OFF_B1 + id] = b_ih1[grow] + b_hh1[grow];
        }
    }
    // ---- decoder/enc1 biases by MFMA col ----
    if (id < 2048) {
        int n = id & 1023;
        int w = n >> 8, u = (n >> 2) & 63, q = n & 3;
        int grow = q * HID + w * 64 + u;
        if (id < 1024) ws[OFF_BN0 + n] = b_ih0[grow] + b_hh0[grow];
        else           ws[OFF_BN1 + n] = b_ih1[grow] + b_hh1[grow];
    }
    // ---- F0 fragments: 9 ks (ks0 = lag block) ----
    if (id < 36864) {
        int ks = id / 4096, rem = id % 4096, nt = rem >> 6, l = rem & 63;
        int n = nt * 16 + (l & 15);
        int w = n >> 8, u = (n >> 2) & 63, q = n & 3;
        int grow = q * HID + w * 64 + u;
        int kbase = (l >> 4) * 8;
        unsigned short h8[8];
        #pragma unroll
        for (int i = 0; i < 8; ++i) {
            float v;
            if (ks == 0) { int k = kbase + i; v = (k < NLAG) ? w_ih0[grow * NLAG + k] : 0.0f; }
            else         { int kk = (ks - 1) * 32 + kbase + i; v = w_hh0[grow * HID + kk]; }
            h8[i] = hbits(v);
        }
        uint4 o;
        o.x = (unsigned int)h8[0] | ((unsigned int)h8[1] << 16);
        o.y = (unsigned int)h8[2] | ((unsigned int)h8[3] << 16);
        o.z = (unsigned int)h8[4] | ((unsigned int)h8[5] << 16);
        o.w = (unsigned int)h8[6] | ((unsigned int)h8[7] << 16);
        ((uint4*)(ws + OFF_F0))[id] = o;
    }
    // ---- F1 fragments: 16 ks (ks<8 = w_ih1, used by enc1 MFMA + decoder) ----
    if (id < 65536) {
        int ks = id >> 12, rem = id & 4095, nt = rem >> 6, l = rem & 63;
        int n = nt * 16 + (l & 15);
        int w = n >> 8, u = (n >> 2) & 63, q = n & 3;
        int grow = q * HID + w * 64 + u;
        int kbase = (l >> 4) * 8;
        unsigned short h8[8];
        #pragma unroll
        for (int i = 0; i < 8; ++i) {
            int kk = ks * 32 + kbase + i;
            float v = (kk < 256) ? w_ih1[grow * HID + kk] : w_hh1[grow * HID + kk - 256];
            h8[i] = hbits(v);
        }
        uint4 o;
        o.x = (unsigned int)h8[0] | ((unsigned int)h8[1] << 16);
        o.y = (unsigned int)h8[2] | ((unsigned int)h8[3] << 16);
        o.z = (unsigned int)h8[4] | ((unsigned int)h8[5] << 16);
        o.w = (unsigned int)h8[6] | ((unsigned int)h8[7] << 16);
        ((uint4*)(ws + OFF_F1))[id] = o;
    }
}

// ---------------- kernel 2: normalize + zero accumulators ----------------
__global__ __launch_bounds__(256) void prep_norm(const float* __restrict__ x,
                                                 float* __restrict__ ws) {
    const int b = blockIdx.x, j = threadIdx.x;
    const float* row = x + b * TLEN;
    float s = 0.0f, s2 = 0.0f;
    for (int t = j; t < WIN; t += 256) {
        float v = row[NLAG + t];
        s += v;
        s2 = fmaf(v, v, s2);
    }
    #pragma unroll
    for (int off = 32; off > 0; off >>= 1) {
        s  += __shfl_down(s, off, 64);
        s2 += __shfl_down(s2, off, 64);
    }
    __shared__ float rs[4], rs2[4];
    __shared__ float sh_loc, sh_scale;
    int wave = j >> 6, lane = j & 63;
    if (lane == 0) { rs[wave] = s; rs2[wave] = s2; }
    __syncthreads();
    if (j == 0) {
        float S = rs[0] + rs[1] + rs[2] + rs[3];
        float S2 = rs2[0] + rs2[1] + rs2[2] + rs2[3];
        float mean = S * (1.0f / WIN);
        float var = S2 * (1.0f / WIN) - mean * mean;
        float sd = sqrtf(fmaxf(var, 0.0f));
        if (sd < 1e-10f) sd = 1.0f;
        sh_loc = mean; sh_scale = sd;
        ws[OFF_LOC + b] = mean;
        ws[OFF_SCALE + b] = sd;
    }
    __syncthreads();
    float loc = sh_loc, inv = 1.0f / sh_scale;
    for (int t = j; t < TLEN; t += 256) {
        ws[OFF_SCALED + b * TLEN + t] = (row[t] - loc) * inv;
    }
    if (j < PRED) ws[OFF_ACC + b * PRED + j] = 0.0f;
}

// ---------------- kernel 3: FUSED pipelined encoder ----------------
// 256 blocks x 1024 threads. Blocks 0..127 run enc0 on chunk tc0; blocks
// 128..255 run enc1 on chunk tc1 = tc0 - TCHUNK. The two roles are
// independent within a launch (enc1(c-1) needs only enc0(c-1)'s traj from
// the PREVIOUS launch); dependencies ride on launch boundaries — no
// cross-block flags (r6: ~90us/round, banned). traj double-buffered by
// (tc/TCHUNK)&1 so enc0's writes never collide with enc1's reads.
struct Smem0 {
    unsigned int h0p[2][128];
    float4 pgs[2][4][256];
    float4 wlag[NLAG * 256];
    float xs[2][NLAG];
};
struct Smem1 {
    float P[16][1028];
    float4 pgs[2][4][256];
    unsigned int h1p[2][128];
};
union SmemU { Smem0 s0; Smem1 s1; };

__global__ __launch_bounds__(1024) void fused_enc(float* __restrict__ ws,
                                                  int tc0, int tc1) {
    __shared__ SmemU sm;
    const int tid = threadIdx.x;
    const int role = blockIdx.x >> 7;
    const int bb = blockIdx.x & 127;
    const int j  = tid & 255;
    const int kq = tid >> 8;

    if (role == 0) {
        // ================= enc0: layer-0 chunk tc0 =================
        if (tc0 < 0) return;
        float c0[2] = {0.0f, 0.0f};
        for (int i = tid; i < NLAG * 256; i += 1024)
            sm.s0.wlag[i] = ((const float4*)(ws + OFF_WIH0))[i];
        const uint4* W0 = (const uint4*)((const unsigned int*)ws + OFF_WHH0H);
        float4 bv0 = {0, 0, 0, 0};
        if (kq == 0) {
            bv0 = ((const float4*)(ws + OFF_B0))[j];
            #pragma unroll
            for (int r = 0; r < 2; ++r) {
                int b = bb * 2 + r;
                if (tc0 == 0) {
                    c0[r] = 0.0f;
                    ((_Float16*)&sm.s0.h0p[r][0])[j] = (_Float16)0.0f;
                } else {
                    c0[r] = ws[OFF_EC0 + b * HID + j];
                    ((_Float16*)&sm.s0.h0p[r][0])[j] = (_Float16)ws[OFF_EH0 + b * HID + j];
                }
            }
        }
        const float* sc0 = ws + OFF_SCALED + (bb * 2 + 0) * TLEN;
        const float* sc1 = ws + OFF_SCALED + (bb * 2 + 1) * TLEN;
        _Float16* traj = (_Float16*)(ws + OFF_TRAJ) +
                         (size_t)((tc0 / TCHUNK) & 1) * TRAJ_HALVES;
        __syncthreads();

        for (int tl = 0; tl < TCHUNK; ++tl) {
            int t = tc0 + tl;
            if (tid < 2 * NLAG) {
                int r = tid / NLAG, f = tid % NLAG;
                sm.s0.xs[r][f] = (r ? sc1 : sc0)[t + 6 - f];
            }
            {
                float4 a0 = {0, 0, 0, 0}, a1 = {0, 0, 0, 0};
                const uint4* Wp = W0 + (kq * 32) * 256 + j;
                const unsigned int* hp0 = &sm.s0.h0p[0][kq * 32];
                const unsigned int* hp1 = &sm.s0.h0p[1][kq * 32];
                #pragma unroll 4
                for (int p = 0; p < 32; ++p) {
                    uint4 w = Wp[p * 256];
                    dot2x4(a0, hp0[p], w);
                    dot2x4(a1, hp1[p], w);
                }
                sm.s0.pgs[0][kq][j] = a0;
                sm.s0.pgs[1][kq][j] = a1;
            }
            __syncthreads();   // pgs + xs ready; reads of h0p done
            if (kq == 0) {
                #pragma unroll
                for (int r = 0; r < 2; ++r) {
                    float4 a = bv0;
                    #pragma unroll
                    for (int f = 0; f < NLAG; ++f) fma4(a, sm.s0.wlag[f * 256 + j], sm.s0.xs[r][f]);
                    #pragma unroll
                    for (int h = 0; h < 4; ++h) {
                        float4 p = sm.s0.pgs[r][h][j];
                        a.x += p.x; a.y += p.y; a.z += p.z; a.w += p.w;
                    }
                    c0[r] = sigm(a.y) * c0[r] + sigm(a.x) * ftanh(a.z);
                    _Float16 hh = (_Float16)(sigm(a.w) * ftanh(c0[r]));
                    ((_Float16*)&sm.s0.h0p[r][0])[j] = hh;
                    traj[((bb * 2 + r) * TCHUNK + tl) * HID + j] = hh;
                }
            }
            __syncthreads();   // h0p(t) visible
        }
        if (kq == 0) {
            #pragma unroll
            for (int r = 0; r < 2; ++r) {
                int b = bb * 2 + r;
                ws[OFF_EH0 + b * HID + j] = (float)((_Float16*)&sm.s0.h0p[r][0])[j];
                ws[OFF_EC0 + b * HID + j] = c0[r];
            }
        }
    } else {
        // ================= enc1: layer-1 chunk tc1 =================
        if (tc1 < 0) return;
        const int lane = tid & 63, wv = tid >> 6;
        const int m16 = lane & 15, q16 = lane >> 4;
        float c1[2] = {0.0f, 0.0f};

        const uint4* F1 = (const uint4*)(ws + OFF_F1);
        const uint4* W1 = (const uint4*)((const unsigned int*)ws + OFF_WCAT1H);
        const float* bn1 = ws + OFF_BN1;
        const _Float16* traj = (const _Float16*)(ws + OFF_TRAJ) +
                               (size_t)((tc1 / TCHUNK) & 1) * TRAJ_HALVES;

        if (kq == 0) {
            #pragma unroll
            for (int r = 0; r < 2; ++r) {
                int b = bb * 2 + r;
                if (tc1 == 0) {
                    c1[r] = 0.0f;
                    ((_Float16*)&sm.s1.h1p[r][0])[j] = (_Float16)0.0f;
                } else {
                    c1[r] = ws[OFF_EC1 + b * HID + j];
                    ((_Float16*)&sm.s1.h1p[r][0])[j] = (_Float16)ws[OFF_EH1 + b * HID + j];
                }
            }
        }
        __syncthreads();

        for (int g8 = 0; g8 < TCHUNK / 8; ++g8) {
            // ---- MFMA batch: P[m][n] = bias + sum_k h0[m][k] * w_ih1[n][k] ----
            {
                const int ntb = wv * 4;
                f32x4 acc[4];
                #pragma unroll
                for (int qq = 0; qq < 4; ++qq) {
                    float b = bn1[(ntb + qq) * 16 + m16];
                    acc[qq] = (f32x4){b, b, b, b};
                }
                #pragma unroll
                for (int ks = 0; ks < 8; ++ks) {
                    const _Float16* ap = traj +
                        (((bb * 2 + (m16 >> 3)) * TCHUNK) + g8 * 8 + (m16 & 7)) * HID +
                        q16 * 8 + ks * 32;
                    half8 av = *(const half8*)ap;
                    #pragma unroll
                    for (int qq = 0; qq < 4; ++qq) {
                        uint4 bw = F1[(ks * 64 + ntb + qq) * 64 + lane];
                        acc[qq] = __builtin_amdgcn_mfma_f32_16x16x32_f16(
                            av, __builtin_bit_cast(half8, bw), acc[qq], 0, 0, 0);
                    }
                }
                #pragma unroll
                for (int qq = 0; qq < 4; ++qq)
                    #pragma unroll
                    for (int rg = 0; rg < 4; ++rg)
                        sm.s1.P[q16 * 4 + rg][(ntb + qq) * 16 + m16] = acc[qq][rg];
            }
            __syncthreads();   // P ready; guards P overwrite vs prior reads
            // ---- 8 sequential sub-steps: recurrent w_hh1 only ----
            for (int ss = 0; ss < 8; ++ss) {
                {
                    float4 a0 = {0, 0, 0, 0}, a1 = {0, 0, 0, 0};
                    const uint4* Wp = W1 + (128 + kq * 32) * 256 + j;
                    const unsigned int* hp0 = &sm.s1.h1p[0][kq * 32];
                    const unsigned int* hp1 = &sm.s1.h1p[1][kq * 32];
                    #pragma unroll 4
                    for (int p = 0; p < 32; ++p) {
                        uint4 w = Wp[p * 256];
                        dot2x4(a0, hp0[p], w);
                        dot2x4(a1, hp1[p], w);
                    }
                    sm.s1.pgs[0][kq][j] = a0;
                    sm.s1.pgs[1][kq][j] = a1;
                }
                __syncthreads();   // pgs ready; reads of h1p done
                if (kq == 0) {
                    #pragma unroll
                    for (int r = 0; r < 2; ++r) {
                        int m = r * 8 + ss;
                        float4 a = *(const float4*)&sm.s1.P[m][j * 4];
                        #pragma unroll
                        for (int h = 0; h < 4; ++h) {
                            float4 p = sm.s1.pgs[r][h][j];
                            a.x += p.x; a.y += p.y; a.z += p.z; a.w += p.w;
                        }
                        c1[r] = sigm(a.y) * c1[r] + sigm(a.x) * ftanh(a.z);
                        ((_Float16*)&sm.s1.h1p[r][0])[j] = (_Float16)(sigm(a.w) * ftanh(c1[r]));
                    }
                }
                __syncthreads();   // h1p(t) visible
            }
        }
        if (kq == 0) {
            #pragma unroll
            for (int r = 0; r < 2; ++r) {
                int b = bb * 2 + r;
                ws[OFF_EH1 + b * HID + j] = (float)((_Float16*)&sm.s1.h1p[r][0])[j];
                ws[OFF_EC1 + b * HID + j] = c1[r];
            }
        }
    }
}

// ---------------- kernel 4: MFMA decoder (r4/r7-verified, RDEC=32, (256,2)) ----------------
// VGPR 128, no spill. DO NOT raise min-occupancy: (256,3) forced VGPR 84 ->
// spill -> 8.4 GB scratch writebacks -> 6.6 ms (r8). (256,2) is the ceiling.
#define RDEC 32
__global__ __launch_bounds__(256, 2) void decoder_kernel(
    const float* __restrict__ wsr,
    const float* __restrict__ w_mu, const float* __restrict__ b_mu,
    const float* __restrict__ w_sigma, const float* __restrict__ b_sigma,
    const float* __restrict__ eps, float* __restrict__ wsw) {
    const int j = threadIdx.x, lane = j & 63, wv = j >> 6;
    const int gr0 = blockIdx.x * RDEC;
    const int m16 = lane & 15, q16 = lane >> 4;
    __shared__ _Float16 hA[2][RDEC][264];   // [layer][row][unit], pad to 264
    __shared__ _Float16 xlag[RDEC][32];     // lag A-tile (k 0..6 live, rest 0)
    __shared__ float scr[4][16][68];        // per-wave D transpose scratch

    const uint4* F0 = (const uint4*)(wsr + OFF_F0);
    const uint4* F1 = (const uint4*)(wsr + OFF_F1);
    const float* bn0 = wsr + OFF_BN0;
    const float* bn1 = wsr + OFF_BN1;

    float c0r[8][4], c1r[8][4];
    for (int r = 0; r < RDEC; ++r) {
        int b = (gr0 + r) / NS;
        hA[0][r][j] = (_Float16)wsr[OFF_EH0 + b * HID + j];
        hA[1][r][j] = (_Float16)wsr[OFF_EH1 + b * HID + j];
    }
    { int r = j >> 3, p = j & 7;
      hA[0][r][256 + p] = (_Float16)0.0f; hA[1][r][256 + p] = (_Float16)0.0f; }
    #pragma unroll
    for (int it = 0; it < 4; ++it) {
        int idx = j + 256 * it;
        int r = idx >> 5, k = idx & 31;
        int b = (gr0 + r) / NS;
        xlag[r][k] = (k < NLAG) ? (_Float16)wsr[OFF_SCALED + b * TLEN + WIN + 6 - k]
                                : (_Float16)0.0f;
    }
    #pragma unroll
    for (int Q = 0; Q < 4; ++Q)
        #pragma unroll
        for (int mt = 0; mt < 2; ++mt) {
            int t2 = Q * 2 + mt;
            int b = (gr0 + mt * 16 + m16) / NS;
            #pragma unroll
            for (int i = 0; i < 4; ++i) {
                int jg = wv * 64 + Q * 16 + q16 * 4 + i;
                c0r[t2][i] = wsr[OFF_EC0 + b * HID + jg];
                c1r[t2][i] = wsr[OFF_EC1 + b * HID + jg];
            }
        }
    __syncthreads();

    float* accg = wsw + OFF_ACC;
    for (int st = 0; st < PRED; ++st) {
        uint2 hnew[8];
        // ================= layer 0 =================
        #pragma unroll 1
        for (int Q = 0; Q < 4; ++Q) {
            f32x4 acc[2][4];
            #pragma unroll
            for (int t = 0; t < 4; ++t) {
                float bb = bn0[wv * 256 + Q * 64 + t * 16 + m16];
                acc[0][t] = (f32x4){bb, bb, bb, bb};
                acc[1][t] = acc[0][t];
            }
            #pragma unroll
            for (int ks = 0; ks < 9; ++ks) {
                uint4 bw[4];
                #pragma unroll
                for (int t = 0; t < 4; ++t)
                    bw[t] = F0[(ks * 64 + wv * 16 + Q * 4 + t) * 64 + lane];
                #pragma unroll
                for (int mt = 0; mt < 2; ++mt) {
                    const _Float16* ap = (ks == 0)
                        ? &xlag[mt * 16 + m16][q16 * 8]
                        : &hA[0][mt * 16 + m16][(ks - 1) * 32 + q16 * 8];
                    half8 av = *(const half8*)ap;
                    #pragma unroll
                    for (int t = 0; t < 4; ++t)
                        acc[mt][t] = __builtin_amdgcn_mfma_f32_16x16x32_f16(
                            av, __builtin_bit_cast(half8, bw[t]), acc[mt][t], 0, 0, 0);
                }
            }
            #pragma unroll
            for (int mt = 0; mt < 2; ++mt) {
                #pragma unroll
                for (int t = 0; t < 4; ++t)
                    #pragma unroll
                    for (int rg = 0; rg < 4; ++rg)
                        scr[wv][q16 * 4 + rg][t * 16 + m16] = acc[mt][t][rg];
                __builtin_amdgcn_wave_barrier();
                int t2 = Q * 2 + mt;
                float hv[4];
                #pragma unroll
                for (int i = 0; i < 4; ++i) {
                    float4 g = *(const float4*)&scr[wv][m16][(q16 * 4 + i) * 4];
                    float c = sigm(g.y) * c0r[t2][i] + sigm(g.x) * ftanh(g.z);
                    c0r[t2][i] = c;
                    hv[i] = sigm(g.w) * ftanh(c);
                }
                __builtin_amdgcn_wave_barrier();
                hnew[t2] = make_uint2(packh2(hv[0], hv[1]), packh2(hv[2], hv[3]));
            }
        }
        __syncthreads();   // all L0 reads of hA[0]/xlag done
        #pragma unroll
        for (int Q = 0; Q < 4; ++Q)
            #pragma unroll
            for (int mt = 0; mt < 2; ++mt)
                *(uint2*)&hA[0][mt * 16 + m16][wv * 64 + Q * 16 + q16 * 4] = hnew[Q * 2 + mt];
        __syncthreads();   // hA[0] now h0(t)
        // ================= layer 1 =================
        #pragma unroll 1
        for (int Q = 0; Q < 4; ++Q) {
            f32x4 acc[2][4];
            #pragma unroll
            for (int t = 0; t < 4; ++t) {
                float bb = bn1[wv * 256 + Q * 64 + t * 16 + m16];
                acc[0][t] = (f32x4){bb, bb, bb, bb};
                acc[1][t] = acc[0][t];
            }
            #pragma unroll
            for (int ks = 0; ks < 16; ++ks) {
                uint4 bw[4];
                #pragma unroll
                for (int t = 0; t < 4; ++t)
                    bw[t] = F1[(ks * 64 + wv * 16 + Q * 4 + t) * 64 + lane];
                #pragma unroll
                for (int mt = 0; mt < 2; ++mt) {
                    const _Float16* ap = (ks < 8)
                        ? &hA[0][mt * 16 + m16][ks * 32 + q16 * 8]
                        : &hA[1][mt * 16 + m16][(ks - 8) * 32 + q16 * 8];
                    half8 av = *(const half8*)ap;
                    #pragma unroll
                    for (int t = 0; t < 4; ++t)
                        acc[mt][t] = __builtin_amdgcn_mfma_f32_16x16x32_f16(
                            av, __builtin_bit_cast(half8, bw[t]), acc[mt][t], 0, 0, 0);
                }
            }
            #pragma unroll
            for (int mt = 0; mt < 2; ++mt) {
                #pragma unroll
                for (int t = 0; t < 4; ++t)
                    #pragma unroll
                    for (int rg = 0; rg < 4; ++rg)
                        scr[wv][q16 * 4 + rg][t * 16 + m16] = acc[mt][t][rg];
                __builtin_amdgcn_wave_barrier();
                int t2 = Q * 2 + mt;
                float hv[4];
                #pragma unroll
                for (int i = 0; i < 4; ++i) {
                    float4 g = *(const float4*)&scr[wv][m16][(q16 * 4 + i) * 4];
                    float c = sigm(g.y) * c1r[t2][i] + sigm(g.x) * ftanh(g.z);
                    c1r[t2][i] = c;
                    hv[i] = sigm(g.w) * ftanh(c);
                }
                __builtin_amdgcn_wave_barrier();
                hnew[t2] = make_uint2(packh2(hv[0], hv[1]), packh2(hv[2], hv[3]));
            }
        }
        __syncthreads();   // all L1 reads of hA done
        #pragma unroll
        for (int Q = 0; Q < 4; ++Q)
            #pragma unroll
            for (int mt = 0; mt < 2; ++mt)
                *(uint2*)&hA[1][mt * 16 + m16][wv * 64 + Q * 16 + q16 * 4] = hnew[Q * 2 + mt];
        __syncthreads();   // hA[1] now h1(t)
        // ================= mu / sigma / sample =================
        #pragma unroll 1
        for (int it = 0; it < 8; ++it) {
            int rr = wv + it * 4;
            uint2 hu = *(const uint2*)&hA[1][rr][lane * 4];
            h2_t p0 = __builtin_bit_cast(h2_t, hu.x);
            h2_t p1 = __builtin_bit_cast(h2_t, hu.y);
            float4 wm = *(const float4*)&w_mu[lane * 4];
            float4 wsg = *(const float4*)&w_sigma[lane * 4];
            float h0f = (float)p0.x, h1f = (float)p0.y, h2f = (float)p1.x, h3f = (float)p1.y;
            float sm = h0f * wm.x + h1f * wm.y + h2f * wm.z + h3f * wm.w;
            float ss = h0f * wsg.x + h1f * wsg.y + h2f * wsg.z + h3f * wsg.w;
            #pragma unroll
            for (int off = 32; off > 0; off >>= 1) {
                sm += __shfl_down(sm, off, 64);
                ss += __shfl_down(ss, off, 64);
            }
            if (lane == 0) {
                float mu = sm + b_mu[0];
                float sg = softplus(ss + b_sigma[0]);
                int gr = gr0 + rr;
                float smp = fmaf(sg, eps[st * GROWS + gr], mu);
                atomicAdd(&accg[(gr / NS) * PRED + st], smp);
                #pragma unroll
                for (int f = NLAG - 1; f >= 1; --f) xlag[rr][f] = xlag[rr][f - 1];
                xlag[rr][0] = (_Float16)smp;
            }
        }
        __syncthreads();   // xlag(t+1) visible
    }
}

// ---------------- kernel 5: finalize ----------------
__global__ __launch_bounds__(256) void finalize_kernel(const float* __restrict__ ws,
                                                       float* __restrict__ out) {
    int i = blockIdx.x * blockDim.x + threadIdx.x;
    if (i < BATCH * PRED) {
        int b = i / PRED;
        out[i] = ws[OFF_ACC + i] * (1.0f / NS) * ws[OFF_SCALE + b] + ws[OFF_LOC + b];
    }
}

// ---------------- launch ----------------
extern "C" void kernel_launch(void* const* d_in, const int* in_sizes, int n_in,
                              void* d_out, int out_size, void* d_ws, size_t ws_size,
                              hipStream_t stream) {
    const float* targets = (const float*)d_in[0];
    const float* w_ih0 = (const float*)d_in[1];
    const float* w_hh0 = (const float*)d_in[2];
    const float* b_ih0 = (const float*)d_in[3];
    const float* b_hh0 = (const float*)d_in[4];
    const float* w_ih1 = (const float*)d_in[5];
    const float* w_hh1 = (const float*)d_in[6];
    const float* b_ih1 = (const float*)d_in[7];
    const float* b_hh1 = (const float*)d_in[8];
    const float* w_mu = (const float*)d_in[9];
    const float* b_mu = (const float*)d_in[10];
    const float* w_sigma = (const float*)d_in[11];
    const float* b_sigma = (const float*)d_in[12];
    const float* eps = (const float*)d_in[13];
    float* ws = (float*)d_ws;
    float* out = (float*)d_out;

    hipLaunchKernelGGL(prep_weights, dim3(1024), dim3(256), 0, stream,
                       w_ih0, w_hh0, b_ih0, b_hh0, w_ih1, w_hh1, b_ih1, b_hh1, ws);
    hipLaunchKernelGGL(prep_norm, dim3(BATCH), dim3(256), 0, stream, targets, ws);
    // Software pipeline: launch c runs enc0(chunk c) || enc1(chunk c-1).
    for (int c = 0; c <= NCHUNK; ++c) {
        int tc0 = (c < NCHUNK) ? c * TCHUNK : -1;
        int tc1 = (c >= 1) ? (c - 1) * TCHUNK : -1;
        hipLaunchKernelGGL(fused_enc, dim3(256), dim3(1024), 0, stream, ws, tc0, tc1);
    }
    hipLaunchKernelGGL(decoder_kernel, dim3(GROWS / RDEC), dim3(256), 0, stream,
                       ws, w_mu, b_mu, w_sigma, b_sigma, eps, ws);
    hipLaunchKernelGGL(finalize_kernel, dim3((BATCH * PRED + 255) / 256), dim3(256), 0,
                       stream, ws, out);
}

// Round 11
// 6224.929 us; speedup vs baseline: 1.9003x; 1.0689x over previous
//
#include <hip/hip_runtime.h>
#include <math.h>

// ---------------- problem constants ----------------
#define BATCH 256
#define TLEN  519          // W + MAXLAG
#define WIN   512
#define HID   256
#define PRED  24
#define NS    100
#define NLAG  7
#define GROWS (BATCH * NS) // 25600 decoder rows
#define TCHUNK 64          // encoder time chunk (8 chunks; double-buffered traj)
#define NCHUNK (WIN / TCHUNK)

// ---------------- workspace layout (float/uint offsets) ----------------
#define OFF_SCALED 0
#define OFF_LOC    132864
#define OFF_SCALE  133120
#define OFF_WIH0   133376   // fp32 [f][j][q], f<7  (encoder lag weights)
#define OFF_WHH0H  140544   // half2 [p][j][q], p<128 (encoder L0 recurrent)
#define OFF_WCAT1H 271616   // half2 [p][j][q], p<256 (p>=128 = w_hh1, enc1 recurrent)
#define OFF_B0     533760   // fp32 combined b_ih0+b_hh0, [j][q]
#define OFF_B1     534784
#define OFF_BN0    535808   // fp32 bias by MFMA col n (layer0)
#define OFF_BN1    536832
#define OFF_F0     537856   // fp16 B-fragments layer0: 9 ks x 64 nt x 64 lane x 8
#define OFF_F1     685312   // fp16 B-fragments layer1: 16 ks x 64 nt x 64 lane x 8
#define OFF_EH0    947456   // encoder states fp32 [b][j] (chunk-carried)
#define OFF_EC0    1012992
#define OFF_EH1    1078528
#define OFF_EC1    1144064
#define OFF_ACC    1209600  // sample accumulators [b][p]
#define OFF_TRAJ   1215744  // fp16 h0 trajectory, 2 buffers x [b][tl<64][256] = 16.8 MB
#define TRAJ_HALVES (BATCH * TCHUNK * HID)   // per buffer: 4,194,304 halves
#define WS_FLOATS  5410048  // 21.6 MB (same footprint as r9/r10)

// ---------------- helpers ----------------
typedef _Float16 h2_t  __attribute__((ext_vector_type(2)));
typedef _Float16 half8 __attribute__((ext_vector_type(8)));
typedef float    f32x4 __attribute__((ext_vector_type(4)));

__device__ __forceinline__ float sigm(float x) { return 1.0f / (1.0f + __expf(-x)); }
__device__ __forceinline__ float ftanh(float x) {
    float e = __expf(2.0f * x);
    return 1.0f - 2.0f / (e + 1.0f);
}
__device__ __forceinline__ float softplus(float x) {
    return (x > 15.0f) ? x : log1pf(__expf(x));
}
__device__ __forceinline__ void fma4(float4& a, const float4 w, const float x) {
    a.x = fmaf(w.x, x, a.x);
    a.y = fmaf(w.y, x, a.y);
    a.z = fmaf(w.z, x, a.z);
    a.w = fmaf(w.w, x, a.w);
}
__device__ __forceinline__ float dot2(unsigned int h, unsigned int w, float acc) {
    return __builtin_amdgcn_fdot2(__builtin_bit_cast(h2_t, h),
                                  __builtin_bit_cast(h2_t, w), acc, false);
}
__device__ __forceinline__ void dot2x4(float4& a, const unsigned int h, const uint4 w) {
    a.x = dot2(h, w.x, a.x);
    a.y = dot2(h, w.y, a.y);
    a.z = dot2(h, w.z, a.z);
    a.w = dot2(h, w.w, a.w);
}
__device__ __forceinline__ unsigned int packh2(float a, float b) {
    h2_t h;
    h.x = (_Float16)a;
    h.y = (_Float16)b;
    return __builtin_bit_cast(unsigned int, h);
}
__device__ __forceinline__ unsigned short hbits(float v) {
    return __builtin_bit_cast(unsigned short, (_Float16)v);
}

// ---------------- kernel 1: repack weights ----------------
__global__ __launch_bounds__(256) void prep_weights(
    const float* __restrict__ w_ih0, const float* __restrict__ w_hh0,
    const float* __restrict__ b_ih0, const float* __restrict__ b_hh0,
    const float* __restrict__ w_ih1, const float* __restrict__ w_hh1,
    const float* __restrict__ b_ih1, const float* __restrict__ b_hh1,
    float* __restrict__ ws) {
    int id = blockIdx.x * blockDim.x + threadIdx.x;   // grid covers 262144
    unsigned int* wsu = (unsigned int*)ws;
    // ---- encoder layouts ----
    {
        int g4 = id & 1023;
        int jj = g4 >> 2, q = g4 & 3;
        int grow = q * HID + jj;
        int p = id >> 10;
        int k0 = 2 * p;
        float v0, v1;
        if (k0 < 256) { v0 = w_ih1[grow * HID + k0];       v1 = w_ih1[grow * HID + k0 + 1]; }
        else          { v0 = w_hh1[grow * HID + k0 - 256]; v1 = w_hh1[grow * HID + k0 - 255]; }
        wsu[OFF_WCAT1H + id] = packh2(v0, v1);
        if (id < 131072) {
            wsu[OFF_WHH0H + id] = packh2(w_hh0[grow * HID + 2 * p], w_hh0[grow * HID + 2 * p + 1]);
        }
        if (id < 7168) {
            int f = id >> 10;
            ws[OFF_WIH0 + id] = w_ih0[grow * NLAG + f];
        }
        if (id < 1024) {
            ws[OFF_B0 + id] = b_ih0[grow] + b_hh0[grow];
            ws[OFF_B1 + id] = b_ih1[grow] + b_hh1[grow];
        }
    }
    // ---- decoder/enc1 biases by MFMA col ----
    if (id < 2048) {
        int n = id & 1023;
        int w = n >> 8, u = (n >> 2) & 63, q = n & 3;
        int grow = q * HID + w * 64 + u;
        if (id < 1024) ws[OFF_BN0 + n] = b_ih0[grow] + b_hh0[grow];
        else           ws[OFF_BN1 + n] = b_ih1[grow] + b_hh1[grow];
    }
    // ---- F0 fragments: 9 ks (ks0 = lag block) ----
    if (id < 36864) {
        int ks = id / 4096, rem = id % 4096, nt = rem >> 6, l = rem & 63;
        int n = nt * 16 + (l & 15);
        int w = n >> 8, u = (n >> 2) & 63, q = n & 3;
        int grow = q * HID + w * 64 + u;
        int kbase = (l >> 4) * 8;
        unsigned short h8[8];
        #pragma unroll
        for (int i = 0; i < 8; ++i) {
            float v;
            if (ks == 0) { int k = kbase + i; v = (k < NLAG) ? w_ih0[grow * NLAG + k] : 0.0f; }
            else         { int kk = (ks - 1) * 32 + kbase + i; v = w_hh0[grow * HID + kk]; }
            h8[i] = hbits(v);
        }
        uint4 o;
        o.x = (unsigned int)h8[0] | ((unsigned int)h8[1] << 16);
        o.y = (unsigned int)h8[2] | ((unsigned int)h8[3] << 16);
        o.z = (unsigned int)h8[4] | ((unsigned int)h8[5] << 16);
        o.w = (unsigned int)h8[6] | ((unsigned int)h8[7] << 16);
        ((uint4*)(ws + OFF_F0))[id] = o;
    }
    // ---- F1 fragments: 16 ks (ks<8 = w_ih1, used by enc1 MFMA + decoder) ----
    if (id < 65536) {
        int ks = id >> 12, rem = id & 4095, nt = rem >> 6, l = rem & 63;
        int n = nt * 16 + (l & 15);
        int w = n >> 8, u = (n >> 2) & 63, q = n & 3;
        int grow = q * HID + w * 64 + u;
        int kbase = (l >> 4) * 8;
        unsigned short h8[8];
        #pragma unroll
        for (int i = 0; i < 8; ++i) {
            int kk = ks * 32 + kbase + i;
            float v = (kk < 256) ? w_ih1[grow * HID + kk] : w_hh1[grow * HID + kk - 256];
            h8[i] = hbits(v);
        }
        uint4 o;
        o.x = (unsigned int)h8[0] | ((unsigned int)h8[1] << 16);
        o.y = (unsigned int)h8[2] | ((unsigned int)h8[3] << 16);
        o.z = (unsigned int)h8[4] | ((unsigned int)h8[5] << 16);
        o.w = (unsigned int)h8[6] | ((unsigned int)h8[7] << 16);
        ((uint4*)(ws + OFF_F1))[id] = o;
    }
}

// ---------------- kernel 2: normalize + zero accumulators ----------------
__global__ __launch_bounds__(256) void prep_norm(const float* __restrict__ x,
                                                 float* __restrict__ ws) {
    const int b = blockIdx.x, j = threadIdx.x;
    const float* row = x + b * TLEN;
    float s = 0.0f, s2 = 0.0f;
    for (int t = j; t < WIN; t += 256) {
        float v = row[NLAG + t];
        s += v;
        s2 = fmaf(v, v, s2);
    }
    #pragma unroll
    for (int off = 32; off > 0; off >>= 1) {
        s  += __shfl_down(s, off, 64);
        s2 += __shfl_down(s2, off, 64);
    }
    __shared__ float rs[4], rs2[4];
    __shared__ float sh_loc, sh_scale;
    int wave = j >> 6, lane = j & 63;
    if (lane == 0) { rs[wave] = s; rs2[wave] = s2; }
    __syncthreads();
    if (j == 0) {
        float S = rs[0] + rs[1] + rs[2] + rs[3];
        float S2 = rs2[0] + rs2[1] + rs2[2] + rs2[3];
        float mean = S * (1.0f / WIN);
        float var = S2 * (1.0f / WIN) - mean * mean;
        float sd = sqrtf(fmaxf(var, 0.0f));
        if (sd < 1e-10f) sd = 1.0f;
        sh_loc = mean; sh_scale = sd;
        ws[OFF_LOC + b] = mean;
        ws[OFF_SCALE + b] = sd;
    }
    __syncthreads();
    float loc = sh_loc, inv = 1.0f / sh_scale;
    for (int t = j; t < TLEN; t += 256) {
        ws[OFF_SCALED + b * TLEN + t] = (row[t] - loc) * inv;
    }
    if (j < PRED) ws[OFF_ACC + b * PRED + j] = 0.0f;
}

// ---------------- kernel 3: FUSED pipelined encoder (r10-verified) ----------------
struct Smem0 {
    unsigned int h0p[2][128];
    float4 pgs[2][4][256];
    float4 wlag[NLAG * 256];
    float xs[2][NLAG];
};
struct Smem1 {
    float P[16][1028];
    float4 pgs[2][4][256];
    unsigned int h1p[2][128];
};
union SmemU { Smem0 s0; Smem1 s1; };

__global__ __launch_bounds__(1024) void fused_enc(float* __restrict__ ws,
                                                  int tc0, int tc1) {
    __shared__ SmemU sm;
    const int tid = threadIdx.x;
    const int role = blockIdx.x >> 7;
    const int bb = blockIdx.x & 127;
    const int j  = tid & 255;
    const int kq = tid >> 8;

    if (role == 0) {
        // ================= enc0: layer-0 chunk tc0 =================
        if (tc0 < 0) return;
        float c0[2] = {0.0f, 0.0f};
        for (int i = tid; i < NLAG * 256; i += 1024)
            sm.s0.wlag[i] = ((const float4*)(ws + OFF_WIH0))[i];
        const uint4* W0 = (const uint4*)((const unsigned int*)ws + OFF_WHH0H);
        float4 bv0 = {0, 0, 0, 0};
        if (kq == 0) {
            bv0 = ((const float4*)(ws + OFF_B0))[j];
            #pragma unroll
            for (int r = 0; r < 2; ++r) {
                int b = bb * 2 + r;
                if (tc0 == 0) {
                    c0[r] = 0.0f;
                    ((_Float16*)&sm.s0.h0p[r][0])[j] = (_Float16)0.0f;
                } else {
                    c0[r] = ws[OFF_EC0 + b * HID + j];
                    ((_Float16*)&sm.s0.h0p[r][0])[j] = (_Float16)ws[OFF_EH0 + b * HID + j];
                }
            }
        }
        const float* sc0 = ws + OFF_SCALED + (bb * 2 + 0) * TLEN;
        const float* sc1 = ws + OFF_SCALED + (bb * 2 + 1) * TLEN;
        _Float16* traj = (_Float16*)(ws + OFF_TRAJ) +
                         (size_t)((tc0 / TCHUNK) & 1) * TRAJ_HALVES;
        __syncthreads();

        for (int tl = 0; tl < TCHUNK; ++tl) {
            int t = tc0 + tl;
            if (tid < 2 * NLAG) {
                int r = tid / NLAG, f = tid % NLAG;
                sm.s0.xs[r][f] = (r ? sc1 : sc0)[t + 6 - f];
            }
            {
                float4 a0 = {0, 0, 0, 0}, a1 = {0, 0, 0, 0};
                const uint4* Wp = W0 + (kq * 32) * 256 + j;
                const unsigned int* hp0 = &sm.s0.h0p[0][kq * 32];
                const unsigned int* hp1 = &sm.s0.h0p[1][kq * 32];
                #pragma unroll 4
                for (int p = 0; p < 32; ++p) {
                    uint4 w = Wp[p * 256];
                    dot2x4(a0, hp0[p], w);
                    dot2x4(a1, hp1[p], w);
                }
                sm.s0.pgs[0][kq][j] = a0;
                sm.s0.pgs[1][kq][j] = a1;
            }
            __syncthreads();   // pgs + xs ready; reads of h0p done
            if (kq == 0) {
                #pragma unroll
                for (int r = 0; r < 2; ++r) {
                    float4 a = bv0;
                    #pragma unroll
                    for (int f = 0; f < NLAG; ++f) fma4(a, sm.s0.wlag[f * 256 + j], sm.s0.xs[r][f]);
                    #pragma unroll
                    for (int h = 0; h < 4; ++h) {
                        float4 p = sm.s0.pgs[r][h][j];
                        a.x += p.x; a.y += p.y; a.z += p.z; a.w += p.w;
                    }
                    c0[r] = sigm(a.y) * c0[r] + sigm(a.x) * ftanh(a.z);
                    _Float16 hh = (_Float16)(sigm(a.w) * ftanh(c0[r]));
                    ((_Float16*)&sm.s0.h0p[r][0])[j] = hh;
                    traj[((bb * 2 + r) * TCHUNK + tl) * HID + j] = hh;
                }
            }
            __syncthreads();   // h0p(t) visible
        }
        if (kq == 0) {
            #pragma unroll
            for (int r = 0; r < 2; ++r) {
                int b = bb * 2 + r;
                ws[OFF_EH0 + b * HID + j] = (float)((_Float16*)&sm.s0.h0p[r][0])[j];
                ws[OFF_EC0 + b * HID + j] = c0[r];
            }
        }
    } else {
        // ================= enc1: layer-1 chunk tc1 =================
        if (tc1 < 0) return;
        const int lane = tid & 63, wv = tid >> 6;
        const int m16 = lane & 15, q16 = lane >> 4;
        float c1[2] = {0.0f, 0.0f};

        const uint4* F1 = (const uint4*)(ws + OFF_F1);
        const uint4* W1 = (const uint4*)((const unsigned int*)ws + OFF_WCAT1H);
        const float* bn1 = ws + OFF_BN1;
        const _Float16* traj = (const _Float16*)(ws + OFF_TRAJ) +
                               (size_t)((tc1 / TCHUNK) & 1) * TRAJ_HALVES;

        if (kq == 0) {
            #pragma unroll
            for (int r = 0; r < 2; ++r) {
                int b = bb * 2 + r;
                if (tc1 == 0) {
                    c1[r] = 0.0f;
                    ((_Float16*)&sm.s1.h1p[r][0])[j] = (_Float16)0.0f;
                } else {
                    c1[r] = ws[OFF_EC1 + b * HID + j];
                    ((_Float16*)&sm.s1.h1p[r][0])[j] = (_Float16)ws[OFF_EH1 + b * HID + j];
                }
            }
        }
        __syncthreads();

        for (int g8 = 0; g8 < TCHUNK / 8; ++g8) {
            // ---- MFMA batch: P[m][n] = bias + sum_k h0[m][k] * w_ih1[n][k] ----
            {
                const int ntb = wv * 4;
                f32x4 acc[4];
                #pragma unroll
                for (int qq = 0; qq < 4; ++qq) {
                    float b = bn1[(ntb + qq) * 16 + m16];
                    acc[qq] = (f32x4){b, b, b, b};
                }
                #pragma unroll
                for (int ks = 0; ks < 8; ++ks) {
                    const _Float16* ap = traj +
                        (((bb * 2 + (m16 >> 3)) * TCHUNK) + g8 * 8 + (m16 & 7)) * HID +
                        q16 * 8 + ks * 32;
                    half8 av = *(const half8*)ap;
                    #pragma unroll
                    for (int qq = 0; qq < 4; ++qq) {
                        uint4 bw = F1[(ks * 64 + ntb + qq) * 64 + lane];
                        acc[qq] = __builtin_amdgcn_mfma_f32_16x16x32_f16(
                            av, __builtin_bit_cast(half8, bw), acc[qq], 0, 0, 0);
                    }
                }
                #pragma unroll
                for (int qq = 0; qq < 4; ++qq)
                    #pragma unroll
                    for (int rg = 0; rg < 4; ++rg)
                        sm.s1.P[q16 * 4 + rg][(ntb + qq) * 16 + m16] = acc[qq][rg];
            }
            __syncthreads();   // P ready; guards P overwrite vs prior reads
            // ---- 8 sequential sub-steps: recurrent w_hh1 only ----
            for (int ss = 0; ss < 8; ++ss) {
                {
                    float4 a0 = {0, 0, 0, 0}, a1 = {0, 0, 0, 0};
                    const uint4* Wp = W1 + (128 + kq * 32) * 256 + j;
                    const unsigned int* hp0 = &sm.s1.h1p[0][kq * 32];
                    const unsigned int* hp1 = &sm.s1.h1p[1][kq * 32];
                    #pragma unroll 4
                    for (int p = 0; p < 32; ++p) {
                        uint4 w = Wp[p * 256];
                        dot2x4(a0, hp0[p], w);
                        dot2x4(a1, hp1[p], w);
                    }
                    sm.s1.pgs[0][kq][j] = a0;
                    sm.s1.pgs[1][kq][j] = a1;
                }
                __syncthreads();   // pgs ready; reads of h1p done
                if (kq == 0) {
                    #pragma unroll
                    for (int r = 0; r < 2; ++r) {
                        int m = r * 8 + ss;
                        float4 a = *(const float4*)&sm.s1.P[m][j * 4];
                        #pragma unroll
                        for (int h = 0; h < 4; ++h) {
                            float4 p = sm.s1.pgs[r][h][j];
                            a.x += p.x; a.y += p.y; a.z += p.z; a.w += p.w;
                        }
                        c1[r] = sigm(a.y) * c1[r] + sigm(a.x) * ftanh(a.z);
                        ((_Float16*)&sm.s1.h1p[r][0])[j] = (_Float16)(sigm(a.w) * ftanh(c1[r]));
                    }
                }
                __syncthreads();   // h1p(t) visible
            }
        }
        if (kq == 0) {
            #pragma unroll
            for (int r = 0; r < 2; ++r) {
                int b = bb * 2 + r;
                ws[OFF_EH1 + b * HID + j] = (float)((_Float16*)&sm.s1.h1p[r][0])[j];
                ws[OFF_EC1 + b * HID + j] = c1[r];
            }
        }
    }
}

// ---------------- kernel 4: MFMA decoder (RDEC=32, (256,2), ks-prefetched) ----------------
// VGPR budget: (256,2) caps at 256/wave; r10 used 128 -> explicit 1-deep
// B-fragment prefetch (+32 regs) attacks the load-latency stall (MfmaUtil
// 12.5%, VALUBusy 33%, 92us/step vs 25us stream floor). DO NOT use (256,3):
// r8 proved it forces VGPR 84 -> spill -> HBM-bound.
#define RDEC 32
__global__ __launch_bounds__(256, 2) void decoder_kernel(
    const float* __restrict__ wsr,
    const float* __restrict__ w_mu, const float* __restrict__ b_mu,
    const float* __restrict__ w_sigma, const float* __restrict__ b_sigma,
    const float* __restrict__ eps, float* __restrict__ wsw) {
    const int j = threadIdx.x, lane = j & 63, wv = j >> 6;
    const int gr0 = blockIdx.x * RDEC;
    const int m16 = lane & 15, q16 = lane >> 4;
    __shared__ _Float16 hA[2][RDEC][264];   // [layer][row][unit], pad to 264
    __shared__ _Float16 xlag[RDEC][32];     // lag A-tile (k 0..6 live, rest 0)
    __shared__ float scr[4][16][68];        // per-wave D transpose scratch

    const uint4* F0 = (const uint4*)(wsr + OFF_F0);
    const uint4* F1 = (const uint4*)(wsr + OFF_F1);
    const float* bn0 = wsr + OFF_BN0;
    const float* bn1 = wsr + OFF_BN1;

    float c0r[8][4], c1r[8][4];
    for (int r = 0; r < RDEC; ++r) {
        int b = (gr0 + r) / NS;
        hA[0][r][j] = (_Float16)wsr[OFF_EH0 + b * HID + j];
        hA[1][r][j] = (_Float16)wsr[OFF_EH1 + b * HID + j];
    }
    { int r = j >> 3, p = j & 7;
      hA[0][r][256 + p] = (_Float16)0.0f; hA[1][r][256 + p] = (_Float16)0.0f; }
    #pragma unroll
    for (int it = 0; it < 4; ++it) {
        int idx = j + 256 * it;
        int r = idx >> 5, k = idx & 31;
        int b = (gr0 + r) / NS;
        xlag[r][k] = (k < NLAG) ? (_Float16)wsr[OFF_SCALED + b * TLEN + WIN + 6 - k]
                                : (_Float16)0.0f;
    }
    #pragma unroll
    for (int Q = 0; Q < 4; ++Q)
        #pragma unroll
        for (int mt = 0; mt < 2; ++mt) {
            int t2 = Q * 2 + mt;
            int b = (gr0 + mt * 16 + m16) / NS;
            #pragma unroll
            for (int i = 0; i < 4; ++i) {
                int jg = wv * 64 + Q * 16 + q16 * 4 + i;
                c0r[t2][i] = wsr[OFF_EC0 + b * HID + jg];
                c1r[t2][i] = wsr[OFF_EC1 + b * HID + jg];
            }
        }
    __syncthreads();

    float* accg = wsw + OFF_ACC;
    for (int st = 0; st < PRED; ++st) {
        uint2 hnew[8];
        // ================= layer 0 =================
        #pragma unroll 1
        for (int Q = 0; Q < 4; ++Q) {
            f32x4 acc[2][4];
            #pragma unroll
            for (int t = 0; t < 4; ++t) {
                float bb = bn0[wv * 256 + Q * 64 + t * 16 + m16];
                acc[0][t] = (f32x4){bb, bb, bb, bb};
                acc[1][t] = acc[0][t];
            }
            uint4 bwc[4], bwn[4];
            #pragma unroll
            for (int t = 0; t < 4; ++t)
                bwc[t] = F0[(0 * 64 + wv * 16 + Q * 4 + t) * 64 + lane];
            #pragma unroll
            for (int ks = 0; ks < 9; ++ks) {
                if (ks < 8) {
                    #pragma unroll
                    for (int t = 0; t < 4; ++t)
                        bwn[t] = F0[((ks + 1) * 64 + wv * 16 + Q * 4 + t) * 64 + lane];
                }
                #pragma unroll
                for (int mt = 0; mt < 2; ++mt) {
                    const _Float16* ap = (ks == 0)
                        ? &xlag[mt * 16 + m16][q16 * 8]
                        : &hA[0][mt * 16 + m16][(ks - 1) * 32 + q16 * 8];
                    half8 av = *(const half8*)ap;
                    #pragma unroll
                    for (int t = 0; t < 4; ++t)
                        acc[mt][t] = __builtin_amdgcn_mfma_f32_16x16x32_f16(
                            av, __builtin_bit_cast(half8, bwc[t]), acc[mt][t], 0, 0, 0);
                }
                #pragma unroll
                for (int t = 0; t < 4; ++t) bwc[t] = bwn[t];
            }
            #pragma unroll
            for (int mt = 0; mt < 2; ++mt) {
                #pragma unroll
                for (int t = 0; t < 4; ++t)
                    #pragma unroll
                    for (int rg = 0; rg < 4; ++rg)
                        scr[wv][q16 * 4 + rg][t * 16 + m16] = acc[mt][t][rg];
                __builtin_amdgcn_wave_barrier();
                int t2 = Q * 2 + mt;
                float hv[4];
                #pragma unroll
                for (int i = 0; i < 4; ++i) {
                    float4 g = *(const float4*)&scr[wv][m16][(q16 * 4 + i) * 4];
                    float c = sigm(g.y) * c0r[t2][i] + sigm(g.x) * ftanh(g.z);
                    c0r[t2][i] = c;
                    hv[i] = sigm(g.w) * ftanh(c);
                }
                __builtin_amdgcn_wave_barrier();
                hnew[t2] = make_uint2(packh2(hv[0], hv[1]), packh2(hv[2], hv[3]));
            }
        }
        __syncthreads();   // all L0 reads of hA[0]/xlag done
        #pragma unroll
        for (int Q = 0; Q < 4; ++Q)
            #pragma unroll
            for (int mt = 0; mt < 2; ++mt)
                *(uint2*)&hA[0][mt * 16 + m16][wv * 64 + Q * 16 + q16 * 4] = hnew[Q * 2 + mt];
        __syncthreads();   // hA[0] now h0(t)
        // ================= layer 1 =================
        #pragma unroll 1
        for (int Q = 0; Q < 4; ++Q) {
            f32x4 acc[2][4];
            #pragma unroll
            for (int t = 0; t < 4; ++t) {
                float bb = bn1[wv * 256 + Q * 64 + t * 16 + m16];
                acc[0][t] = (f32x4){bb, bb, bb, bb};
                acc[1][t] = acc[0][t];
            }
            uint4 bwc[4], bwn[4];
            #pragma unroll
            for (int t = 0; t < 4; ++t)
                bwc[t] = F1[(0 * 64 + wv * 16 + Q * 4 + t) * 64 + lane];
            #pragma unroll
            for (int ks = 0; ks < 16; ++ks) {
                if (ks < 15) {
                    #pragma unroll
                    for (int t = 0; t < 4; ++t)
                        bwn[t] = F1[((ks + 1) * 64 + wv * 16 + Q * 4 + t) * 64 + lane];
                }
                #pragma unroll
                for (int mt = 0; mt < 2; ++mt) {
                    const _Float16* ap = (ks < 8)
                        ? &hA[0][mt * 16 + m16][ks * 32 + q16 * 8]
                        : &hA[1][mt * 16 + m16][(ks - 8) * 32 + q16 * 8];
                    half8 av = *(const half8*)ap;
                    #pragma unroll
                    for (int t = 0; t < 4; ++t)
                        acc[mt][t] = __builtin_amdgcn_mfma_f32_16x16x32_f16(
                            av, __builtin_bit_cast(half8, bwc[t]), acc[mt][t], 0, 0, 0);
                }
                #pragma unroll
                for (int t = 0; t < 4; ++t) bwc[t] = bwn[t];
            }
            #pragma unroll
            for (int mt = 0; mt < 2; ++mt) {
                #pragma unroll
                for (int t = 0; t < 4; ++t)
                    #pragma unroll
                    for (int rg = 0; rg < 4; ++rg)
                        scr[wv][q16 * 4 + rg][t * 16 + m16] = acc[mt][t][rg];
                __builtin_amdgcn_wave_barrier();
                int t2 = Q * 2 + mt;
                float hv[4];
                #pragma unroll
                for (int i = 0; i < 4; ++i) {
                    float4 g = *(const float4*)&scr[wv][m16][(q16 * 4 + i) * 4];
                    float c = sigm(g.y) * c1r[t2][i] + sigm(g.x) * ftanh(g.z);
                    c1r[t2][i] = c;
                    hv[i] = sigm(g.w) * ftanh(c);
                }
                __builtin_amdgcn_wave_barrier();
                hnew[t2] = make_uint2(packh2(hv[0], hv[1]), packh2(hv[2], hv[3]));
            }
        }
        __syncthreads();   // all L1 reads of hA done
        #pragma unroll
        for (int Q = 0; Q < 4; ++Q)
            #pragma unroll
            for (int mt = 0; mt < 2; ++mt)
                *(uint2*)&hA[1][mt * 16 + m16][wv * 64 + Q * 16 + q16 * 4] = hnew[Q * 2 + mt];
        __syncthreads();   // hA[1] now h1(t)
        // ================= mu / sigma / sample (half-wave parallel) =================
        {
            const int half = lane >> 5, lane32 = lane & 31;
            #pragma unroll 1
            for (int it = 0; it < 4; ++it) {
                int rr = wv * 2 + half + it * 8;
                uint4 hu = *(const uint4*)&hA[1][rr][lane32 * 8];
                float4 wmA = *(const float4*)&w_mu[lane32 * 8];
                float4 wmB = *(const float4*)&w_mu[lane32 * 8 + 4];
                float4 wsA = *(const float4*)&w_sigma[lane32 * 8];
                float4 wsB = *(const float4*)&w_sigma[lane32 * 8 + 4];
                h2_t p0 = __builtin_bit_cast(h2_t, hu.x);
                h2_t p1 = __builtin_bit_cast(h2_t, hu.y);
                h2_t p2 = __builtin_bit_cast(h2_t, hu.z);
                h2_t p3 = __builtin_bit_cast(h2_t, hu.w);
                float h0f = (float)p0.x, h1f = (float)p0.y, h2f = (float)p1.x, h3f = (float)p1.y;
                float h4f = (float)p2.x, h5f = (float)p2.y, h6f = (float)p3.x, h7f = (float)p3.y;
                float sm = h0f * wmA.x + h1f * wmA.y + h2f * wmA.z + h3f * wmA.w
                         + h4f * wmB.x + h5f * wmB.y + h6f * wmB.z + h7f * wmB.w;
                float ss = h0f * wsA.x + h1f * wsA.y + h2f * wsA.z + h3f * wsA.w
                         + h4f * wsB.x + h5f * wsB.y + h6f * wsB.z + h7f * wsB.w;
                #pragma unroll
                for (int off = 16; off > 0; off >>= 1) {
                    sm += __shfl_down(sm, off, 32);
                    ss += __shfl_down(ss, off, 32);
                }
                if (lane32 == 0) {
                    float mu = sm + b_mu[0];
                    float sg = softplus(ss + b_sigma[0]);
                    int gr = gr0 + rr;
                    float smp = fmaf(sg, eps[st * GROWS + gr], mu);
                    atomicAdd(&accg[(gr / NS) * PRED + st], smp);
                    #pragma unroll
                    for (int f = NLAG - 1; f >= 1; --f) xlag[rr][f] = xlag[rr][f - 1];
                    xlag[rr][0] = (_Float16)smp;
                }
            }
        }
        __syncthreads();   // xlag(t+1) visible
    }
}

// ---------------- kernel 5: finalize ----------------
__global__ __launch_bounds__(256) void finalize_kernel(const float* __restrict__ ws,
                                                       float* __restrict__ out) {
    int i = blockIdx.x * blockDim.x + threadIdx.x;
    if (i < BATCH * PRED) {
        int b = i / PRED;
        out[i] = ws[OFF_ACC + i] * (1.0f / NS) * ws[OFF_SCALE + b] + ws[OFF_LOC + b];
    }
}

// ---------------- launch ----------------
extern "C" void kernel_launch(void* const* d_in, const int* in_sizes, int n_in,
                              void* d_out, int out_size, void* d_ws, size_t ws_size,
                              hipStream_t stream) {
    const float* targets = (const float*)d_in[0];
    const float* w_ih0 = (const float*)d_in[1];
    const float* w_hh0 = (const float*)d_in[2];
    const float* b_ih0 = (const float*)d_in[3];
    const float* b_hh0 = (const float*)d_in[4];
    const float* w_ih1 = (const float*)d_in[5];
    const float* w_hh1 = (const float*)d_in[6];
    const float* b_ih1 = (const float*)d_in[7];
    const float* b_hh1 = (const float*)d_in[8];
    const float* w_mu = (const float*)d_in[9];
    const float* b_mu = (const float*)d_in[10];
    const float* w_sigma = (const float*)d_in[11];
    const float* b_sigma = (const float*)d_in[12];
    const float* eps = (const float*)d_in[13];
    float* ws = (float*)d_ws;
    float* out = (float*)d_out;

    hipLaunchKernelGGL(prep_weights, dim3(1024), dim3(256), 0, stream,
                       w_ih0, w_hh0, b_ih0, b_hh0, w_ih1, w_hh1, b_ih1, b_hh1, ws);
    hipLaunchKernelGGL(prep_norm, dim3(BATCH), dim3(256), 0, stream, targets, ws);
    // Software pipeline: launch c runs enc0(chunk c) || enc1(chunk c-1).
    for (int c = 0; c <= NCHUNK; ++c) {
        int tc0 = (c < NCHUNK) ? c * TCHUNK : -1;
        int tc1 = (c >= 1) ? (c - 1) * TCHUNK : -1;
        hipLaunchKernelGGL(fused_enc, dim3(256), dim3(1024), 0, stream, ws, tc0, tc1);
    }
    hipLaunchKernelGGL(decoder_kernel, dim3(GROWS / RDEC), dim3(256), 0, stream,
                       ws, w_mu, b_mu, w_sigma, b_sigma, eps, ws);
    hipLaunchKernelGGL(finalize_kernel, dim3((BATCH * PRED + 255) / 256), dim3(256), 0,
                       stream, ws, out);
}

// Round 12
// 5609.447 us; speedup vs baseline: 2.1089x; 1.1097x over previous
//
#include <hip/hip_runtime.h>
#include <math.h>

// ---------------- problem constants ----------------
#define BATCH 256
#define TLEN  519          // W + MAXLAG
#define WIN   512
#define HID   256
#define PRED  24
#define NS    100
#define NLAG  7
#define GROWS (BATCH * NS) // 25600 decoder rows
#define TCHUNK 64          // encoder time chunk (8 chunks; double-buffered traj)
#define NCHUNK (WIN / TCHUNK)

// ---------------- workspace layout (float/uint offsets) ----------------
#define OFF_SCALED 0
#define OFF_LOC    132864
#define OFF_SCALE  133120
#define OFF_WIH0   133376   // fp32 [f][j][q], f<7  (encoder lag weights)
#define OFF_WHH0H  140544   // half2 [p][j][q], p<128 (encoder L0 recurrent)
#define OFF_WCAT1H 271616   // half2 [p][j][q], p<256 (p>=128 = w_hh1, enc1 recurrent)
#define OFF_B0     533760   // fp32 combined b_ih0+b_hh0, [j][q]
#define OFF_B1     534784
#define OFF_BN0    535808   // fp32 bias by MFMA col n (layer0)
#define OFF_BN1    536832
#define OFF_F0     537856   // fp16 B-fragments layer0: 9 ks x 64 nt x 64 lane x 8
#define OFF_F1     685312   // fp16 B-fragments layer1: 16 ks x 64 nt x 64 lane x 8
#define OFF_EH0    947456   // encoder states fp32 [b][j] (chunk-carried)
#define OFF_EC0    1012992
#define OFF_EH1    1078528
#define OFF_EC1    1144064
#define OFF_ACC    1209600  // sample accumulators [b][p]
#define OFF_TRAJ   1215744  // fp16 h0 trajectory, 2 buffers x [b][tl<64][256] = 16.8 MB
#define TRAJ_HALVES (BATCH * TCHUNK * HID)   // per buffer: 4,194,304 halves
#define WS_FLOATS  5410048  // 21.6 MB

// ---------------- helpers ----------------
typedef _Float16 h2_t  __attribute__((ext_vector_type(2)));
typedef _Float16 half8 __attribute__((ext_vector_type(8)));
typedef float    f32x4 __attribute__((ext_vector_type(4)));

__device__ __forceinline__ float sigm(float x) { return 1.0f / (1.0f + __expf(-x)); }
__device__ __forceinline__ float ftanh(float x) {
    float e = __expf(2.0f * x);
    return 1.0f - 2.0f / (e + 1.0f);
}
__device__ __forceinline__ float softplus(float x) {
    return (x > 15.0f) ? x : log1pf(__expf(x));
}
__device__ __forceinline__ void fma4(float4& a, const float4 w, const float x) {
    a.x = fmaf(w.x, x, a.x);
    a.y = fmaf(w.y, x, a.y);
    a.z = fmaf(w.z, x, a.z);
    a.w = fmaf(w.w, x, a.w);
}
__device__ __forceinline__ float dot2(unsigned int h, unsigned int w, float acc) {
    return __builtin_amdgcn_fdot2(__builtin_bit_cast(h2_t, h),
                                  __builtin_bit_cast(h2_t, w), acc, false);
}
__device__ __forceinline__ void dot2x4(float4& a, const unsigned int h, const uint4 w) {
    a.x = dot2(h, w.x, a.x);
    a.y = dot2(h, w.y, a.y);
    a.z = dot2(h, w.z, a.z);
    a.w = dot2(h, w.w, a.w);
}
__device__ __forceinline__ unsigned int packh2(float a, float b) {
    h2_t h;
    h.x = (_Float16)a;
    h.y = (_Float16)b;
    return __builtin_bit_cast(unsigned int, h);
}
__device__ __forceinline__ unsigned short hbits(float v) {
    return __builtin_bit_cast(unsigned short, (_Float16)v);
}

// ---------------- kernel 1: repack weights ----------------
__global__ __launch_bounds__(256) void prep_weights(
    const float* __restrict__ w_ih0, const float* __restrict__ w_hh0,
    const float* __restrict__ b_ih0, const float* __restrict__ b_hh0,
    const float* __restrict__ w_ih1, const float* __restrict__ w_hh1,
    const float* __restrict__ b_ih1, const float* __restrict__ b_hh1,
    float* __restrict__ ws) {
    int id = blockIdx.x * blockDim.x + threadIdx.x;   // grid covers 262144
    unsigned int* wsu = (unsigned int*)ws;
    // ---- encoder layouts ----
    {
        int g4 = id & 1023;
        int jj = g4 >> 2, q = g4 & 3;
        int grow = q * HID + jj;
        int p = id >> 10;
        int k0 = 2 * p;
        float v0, v1;
        if (k0 < 256) { v0 = w_ih1[grow * HID + k0];       v1 = w_ih1[grow * HID + k0 + 1]; }
        else          { v0 = w_hh1[grow * HID + k0 - 256]; v1 = w_hh1[grow * HID + k0 - 255]; }
        wsu[OFF_WCAT1H + id] = packh2(v0, v1);
        if (id < 131072) {
            wsu[OFF_WHH0H + id] = packh2(w_hh0[grow * HID + 2 * p], w_hh0[grow * HID + 2 * p + 1]);
        }
        if (id < 7168) {
            int f = id >> 10;
            ws[OFF_WIH0 + id] = w_ih0[grow * NLAG + f];
        }
        if (id < 1024) {
            ws[OFF_B0 + id] = b_ih0[grow] + b_hh0[grow];
            ws[OFF_B1 + id] = b_ih1[grow] + b_hh1[grow];
        }
    }
    // ---- decoder/enc1 biases by MFMA col ----
    if (id < 2048) {
        int n = id & 1023;
        int w = n >> 8, u = (n >> 2) & 63, q = n & 3;
        int grow = q * HID + w * 64 + u;
        if (id < 1024) ws[OFF_BN0 + n] = b_ih0[grow] + b_hh0[grow];
        else           ws[OFF_BN1 + n] = b_ih1[grow] + b_hh1[grow];
    }
    // ---- F0 fragments: 9 ks (ks0 = lag block) ----
    if (id < 36864) {
        int ks = id / 4096, rem = id % 4096, nt = rem >> 6, l = rem & 63;
        int n = nt * 16 + (l & 15);
        int w = n >> 8, u = (n >> 2) & 63, q = n & 3;
        int grow = q * HID + w * 64 + u;
        int kbase = (l >> 4) * 8;
        unsigned short h8[8];
        #pragma unroll
        for (int i = 0; i < 8; ++i) {
            float v;
            if (ks == 0) { int k = kbase + i; v = (k < NLAG) ? w_ih0[grow * NLAG + k] : 0.0f; }
            else         { int kk = (ks - 1) * 32 + kbase + i; v = w_hh0[grow * HID + kk]; }
            h8[i] = hbits(v);
        }
        uint4 o;
        o.x = (unsigned int)h8[0] | ((unsigned int)h8[1] << 16);
        o.y = (unsigned int)h8[2] | ((unsigned int)h8[3] << 16);
        o.z = (unsigned int)h8[4] | ((unsigned int)h8[5] << 16);
        o.w = (unsigned int)h8[6] | ((unsigned int)h8[7] << 16);
        ((uint4*)(ws + OFF_F0))[id] = o;
    }
    // ---- F1 fragments: 16 ks (ks<8 = w_ih1, used by enc1 MFMA + decoder) ----
    if (id < 65536) {
        int ks = id >> 12, rem = id & 4095, nt = rem >> 6, l = rem & 63;
        int n = nt * 16 + (l & 15);
        int w = n >> 8, u = (n >> 2) & 63, q = n & 3;
        int grow = q * HID + w * 64 + u;
        int kbase = (l >> 4) * 8;
        unsigned short h8[8];
        #pragma unroll
        for (int i = 0; i < 8; ++i) {
            int kk = ks * 32 + kbase + i;
            float v = (kk < 256) ? w_ih1[grow * HID + kk] : w_hh1[grow * HID + kk - 256];
            h8[i] = hbits(v);
        }
        uint4 o;
        o.x = (unsigned int)h8[0] | ((unsigned int)h8[1] << 16);
        o.y = (unsigned int)h8[2] | ((unsigned int)h8[3] << 16);
        o.z = (unsigned int)h8[4] | ((unsigned int)h8[5] << 16);
        o.w = (unsigned int)h8[6] | ((unsigned int)h8[7] << 16);
        ((uint4*)(ws + OFF_F1))[id] = o;
    }
}

// ---------------- kernel 2: normalize + zero accumulators ----------------
__global__ __launch_bounds__(256) void prep_norm(const float* __restrict__ x,
                                                 float* __restrict__ ws) {
    const int b = blockIdx.x, j = threadIdx.x;
    const float* row = x + b * TLEN;
    float s = 0.0f, s2 = 0.0f;
    for (int t = j; t < WIN; t += 256) {
        float v = row[NLAG + t];
        s += v;
        s2 = fmaf(v, v, s2);
    }
    #pragma unroll
    for (int off = 32; off > 0; off >>= 1) {
        s  += __shfl_down(s, off, 64);
        s2 += __shfl_down(s2, off, 64);
    }
    __shared__ float rs[4], rs2[4];
    __shared__ float sh_loc, sh_scale;
    int wave = j >> 6, lane = j & 63;
    if (lane == 0) { rs[wave] = s; rs2[wave] = s2; }
    __syncthreads();
    if (j == 0) {
        float S = rs[0] + rs[1] + rs[2] + rs[3];
        float S2 = rs2[0] + rs2[1] + rs2[2] + rs2[3];
        float mean = S * (1.0f / WIN);
        float var = S2 * (1.0f / WIN) - mean * mean;
        float sd = sqrtf(fmaxf(var, 0.0f));
        if (sd < 1e-10f) sd = 1.0f;
        sh_loc = mean; sh_scale = sd;
        ws[OFF_LOC + b] = mean;
        ws[OFF_SCALE + b] = sd;
    }
    __syncthreads();
    float loc = sh_loc, inv = 1.0f / sh_scale;
    for (int t = j; t < TLEN; t += 256) {
        ws[OFF_SCALED + b * TLEN + t] = (row[t] - loc) * inv;
    }
    if (j < PRED) ws[OFF_ACC + b * PRED + j] = 0.0f;
}

// ---------------- kernel 3: FUSED pipelined encoder (r10-verified) ----------------
struct Smem0 {
    unsigned int h0p[2][128];
    float4 pgs[2][4][256];
    float4 wlag[NLAG * 256];
    float xs[2][NLAG];
};
struct Smem1 {
    float P[16][1028];
    float4 pgs[2][4][256];
    unsigned int h1p[2][128];
};
union SmemU { Smem0 s0; Smem1 s1; };

__global__ __launch_bounds__(1024) void fused_enc(float* __restrict__ ws,
                                                  int tc0, int tc1) {
    __shared__ SmemU sm;
    const int tid = threadIdx.x;
    const int role = blockIdx.x >> 7;
    const int bb = blockIdx.x & 127;
    const int j  = tid & 255;
    const int kq = tid >> 8;

    if (role == 0) {
        // ================= enc0: layer-0 chunk tc0 =================
        if (tc0 < 0) return;
        float c0[2] = {0.0f, 0.0f};
        for (int i = tid; i < NLAG * 256; i += 1024)
            sm.s0.wlag[i] = ((const float4*)(ws + OFF_WIH0))[i];
        const uint4* W0 = (const uint4*)((const unsigned int*)ws + OFF_WHH0H);
        float4 bv0 = {0, 0, 0, 0};
        if (kq == 0) {
            bv0 = ((const float4*)(ws + OFF_B0))[j];
            #pragma unroll
            for (int r = 0; r < 2; ++r) {
                int b = bb * 2 + r;
                if (tc0 == 0) {
                    c0[r] = 0.0f;
                    ((_Float16*)&sm.s0.h0p[r][0])[j] = (_Float16)0.0f;
                } else {
                    c0[r] = ws[OFF_EC0 + b * HID + j];
                    ((_Float16*)&sm.s0.h0p[r][0])[j] = (_Float16)ws[OFF_EH0 + b * HID + j];
                }
            }
        }
        const float* sc0 = ws + OFF_SCALED + (bb * 2 + 0) * TLEN;
        const float* sc1 = ws + OFF_SCALED + (bb * 2 + 1) * TLEN;
        _Float16* traj = (_Float16*)(ws + OFF_TRAJ) +
                         (size_t)((tc0 / TCHUNK) & 1) * TRAJ_HALVES;
        __syncthreads();

        for (int tl = 0; tl < TCHUNK; ++tl) {
            int t = tc0 + tl;
            if (tid < 2 * NLAG) {
                int r = tid / NLAG, f = tid % NLAG;
                sm.s0.xs[r][f] = (r ? sc1 : sc0)[t + 6 - f];
            }
            {
                float4 a0 = {0, 0, 0, 0}, a1 = {0, 0, 0, 0};
                const uint4* Wp = W0 + (kq * 32) * 256 + j;
                const unsigned int* hp0 = &sm.s0.h0p[0][kq * 32];
                const unsigned int* hp1 = &sm.s0.h0p[1][kq * 32];
                #pragma unroll 4
                for (int p = 0; p < 32; ++p) {
                    uint4 w = Wp[p * 256];
                    dot2x4(a0, hp0[p], w);
                    dot2x4(a1, hp1[p], w);
                }
                sm.s0.pgs[0][kq][j] = a0;
                sm.s0.pgs[1][kq][j] = a1;
            }
            __syncthreads();   // pgs + xs ready; reads of h0p done
            if (kq == 0) {
                #pragma unroll
                for (int r = 0; r < 2; ++r) {
                    float4 a = bv0;
                    #pragma unroll
                    for (int f = 0; f < NLAG; ++f) fma4(a, sm.s0.wlag[f * 256 + j], sm.s0.xs[r][f]);
                    #pragma unroll
                    for (int h = 0; h < 4; ++h) {
                        float4 p = sm.s0.pgs[r][h][j];
                        a.x += p.x; a.y += p.y; a.z += p.z; a.w += p.w;
                    }
                    c0[r] = sigm(a.y) * c0[r] + sigm(a.x) * ftanh(a.z);
                    _Float16 hh = (_Float16)(sigm(a.w) * ftanh(c0[r]));
                    ((_Float16*)&sm.s0.h0p[r][0])[j] = hh;
                    traj[((bb * 2 + r) * TCHUNK + tl) * HID + j] = hh;
                }
            }
            __syncthreads();   // h0p(t) visible
        }
        if (kq == 0) {
            #pragma unroll
            for (int r = 0; r < 2; ++r) {
                int b = bb * 2 + r;
                ws[OFF_EH0 + b * HID + j] = (float)((_Float16*)&sm.s0.h0p[r][0])[j];
                ws[OFF_EC0 + b * HID + j] = c0[r];
            }
        }
    } else {
        // ================= enc1: layer-1 chunk tc1 =================
        if (tc1 < 0) return;
        const int lane = tid & 63, wv = tid >> 6;
        const int m16 = lane & 15, q16 = lane >> 4;
        float c1[2] = {0.0f, 0.0f};

        const uint4* F1 = (const uint4*)(ws + OFF_F1);
        const uint4* W1 = (const uint4*)((const unsigned int*)ws + OFF_WCAT1H);
        const float* bn1 = ws + OFF_BN1;
        const _Float16* traj = (const _Float16*)(ws + OFF_TRAJ) +
                               (size_t)((tc1 / TCHUNK) & 1) * TRAJ_HALVES;

        if (kq == 0) {
            #pragma unroll
            for (int r = 0; r < 2; ++r) {
                int b = bb * 2 + r;
                if (tc1 == 0) {
                    c1[r] = 0.0f;
                    ((_Float16*)&sm.s1.h1p[r][0])[j] = (_Float16)0.0f;
                } else {
                    c1[r] = ws[OFF_EC1 + b * HID + j];
                    ((_Float16*)&sm.s1.h1p[r][0])[j] = (_Float16)ws[OFF_EH1 + b * HID + j];
                }
            }
        }
        __syncthreads();

        for (int g8 = 0; g8 < TCHUNK / 8; ++g8) {
            // ---- MFMA batch: P[m][n] = bias + sum_k h0[m][k] * w_ih1[n][k] ----
            {
                const int ntb = wv * 4;
                f32x4 acc[4];
                #pragma unroll
                for (int qq = 0; qq < 4; ++qq) {
                    float b = bn1[(ntb + qq) * 16 + m16];
                    acc[qq] = (f32x4){b, b, b, b};
                }
                #pragma unroll
                for (int ks = 0; ks < 8; ++ks) {
                    const _Float16* ap = traj +
                        (((bb * 2 + (m16 >> 3)) * TCHUNK) + g8 * 8 + (m16 & 7)) * HID +
                        q16 * 8 + ks * 32;
                    half8 av = *(const half8*)ap;
                    #pragma unroll
                    for (int qq = 0; qq < 4; ++qq) {
                        uint4 bw = F1[(ks * 64 + ntb + qq) * 64 + lane];
                        acc[qq] = __builtin_amdgcn_mfma_f32_16x16x32_f16(
                            av, __builtin_bit_cast(half8, bw), acc[qq], 0, 0, 0);
                    }
                }
                #pragma unroll
                for (int qq = 0; qq < 4; ++qq)
                    #pragma unroll
                    for (int rg = 0; rg < 4; ++rg)
                        sm.s1.P[q16 * 4 + rg][(ntb + qq) * 16 + m16] = acc[qq][rg];
            }
            __syncthreads();   // P ready; guards P overwrite vs prior reads
            // ---- 8 sequential sub-steps: recurrent w_hh1 only ----
            for (int ss = 0; ss < 8; ++ss) {
                {
                    float4 a0 = {0, 0, 0, 0}, a1 = {0, 0, 0, 0};
                    const uint4* Wp = W1 + (128 + kq * 32) * 256 + j;
                    const unsigned int* hp0 = &sm.s1.h1p[0][kq * 32];
                    const unsigned int* hp1 = &sm.s1.h1p[1][kq * 32];
                    #pragma unroll 4
                    for (int p = 0; p < 32; ++p) {
                        uint4 w = Wp[p * 256];
                        dot2x4(a0, hp0[p], w);
                        dot2x4(a1, hp1[p], w);
                    }
                    sm.s1.pgs[0][kq][j] = a0;
                    sm.s1.pgs[1][kq][j] = a1;
                }
                __syncthreads();   // pgs ready; reads of h1p done
                if (kq == 0) {
                    #pragma unroll
                    for (int r = 0; r < 2; ++r) {
                        int m = r * 8 + ss;
                        float4 a = *(const float4*)&sm.s1.P[m][j * 4];
                        #pragma unroll
                        for (int h = 0; h < 4; ++h) {
                            float4 p = sm.s1.pgs[r][h][j];
                            a.x += p.x; a.y += p.y; a.z += p.z; a.w += p.w;
                        }
                        c1[r] = sigm(a.y) * c1[r] + sigm(a.x) * ftanh(a.z);
                        ((_Float16*)&sm.s1.h1p[r][0])[j] = (_Float16)(sigm(a.w) * ftanh(c1[r]));
                    }
                }
                __syncthreads();   // h1p(t) visible
            }
        }
        if (kq == 0) {
            #pragma unroll
            for (int r = 0; r < 2; ++r) {
                int b = bb * 2 + r;
                ws[OFF_EH1 + b * HID + j] = (float)((_Float16*)&sm.s1.h1p[r][0])[j];
                ws[OFF_EC1 + b * HID + j] = c1[r];
            }
        }
    }
}

// ---------------- kernel 4: MFMA decoder — 8 waves (TLP x2) ----------------
// 800 blocks x 512 threads. Wave wv (0..7) owns 8 n-tiles (gate cols
// [wv*128,(wv+1)*128)), Q in {0,1}. Per-thread persistent state halves vs
// r11 (c-state 32 floats, hnew 8) so the (512,2) VGPR cap of 128 holds
// (r11 met 128 with MORE state). LDS 69 KB x2 = 141 <= 160 KB -> 2
// blocks/CU = 16 waves/CU = 4 waves/SIMD (2x latency hiding vs r11).
// Spill tripwire: WRITE_SIZE (r3/r5/r8 lesson).
#define RDEC 32
__global__ __launch_bounds__(512, 2) void decoder_kernel(
    const float* __restrict__ wsr,
    const float* __restrict__ w_mu, const float* __restrict__ b_mu,
    const float* __restrict__ w_sigma, const float* __restrict__ b_sigma,
    const float* __restrict__ eps, float* __restrict__ wsw) {
    const int tid = threadIdx.x, lane = tid & 63, wv = tid >> 6;   // 8 waves
    const int j = tid & 255;
    const int gr0 = blockIdx.x * RDEC;
    const int m16 = lane & 15, q16 = lane >> 4;
    __shared__ _Float16 hA[2][RDEC][264];   // [layer][row][unit], pad to 264
    __shared__ _Float16 xlag[RDEC][32];     // lag A-tile (k 0..6 live, rest 0)
    __shared__ float scr[8][16][68];        // per-wave D transpose scratch

    const uint4* F0 = (const uint4*)(wsr + OFF_F0);
    const uint4* F1 = (const uint4*)(wsr + OFF_F1);
    const float* bn0 = wsr + OFF_BN0;
    const float* bn1 = wsr + OFF_BN1;

    float c0r[4][4], c1r[4][4];
    for (int r = tid >> 8; r < RDEC; r += 2) {
        int b = (gr0 + r) / NS;
        hA[0][r][j] = (_Float16)wsr[OFF_EH0 + b * HID + j];
        hA[1][r][j] = (_Float16)wsr[OFF_EH1 + b * HID + j];
    }
    if (tid < 256) {
        int r = tid >> 3, p = tid & 7;
        hA[0][r][256 + p] = (_Float16)0.0f;
        hA[1][r][256 + p] = (_Float16)0.0f;
    }
    #pragma unroll
    for (int it = 0; it < 2; ++it) {
        int idx = tid + 512 * it;
        int r = idx >> 5, k = idx & 31;
        int b = (gr0 + r) / NS;
        xlag[r][k] = (k < NLAG) ? (_Float16)wsr[OFF_SCALED + b * TLEN + WIN + 6 - k]
                                : (_Float16)0.0f;
    }
    #pragma unroll
    for (int Q = 0; Q < 2; ++Q)
        #pragma unroll
        for (int mt = 0; mt < 2; ++mt) {
            int t2 = Q * 2 + mt;
            int b = (gr0 + mt * 16 + m16) / NS;
            #pragma unroll
            for (int i = 0; i < 4; ++i) {
                int jg = wv * 32 + Q * 16 + q16 * 4 + i;
                c0r[t2][i] = wsr[OFF_EC0 + b * HID + jg];
                c1r[t2][i] = wsr[OFF_EC1 + b * HID + jg];
            }
        }
    __syncthreads();

    float* accg = wsw + OFF_ACC;
    for (int st = 0; st < PRED; ++st) {
        uint2 hnew[4];
        // ================= layer 0 =================
        #pragma unroll 1
        for (int Q = 0; Q < 2; ++Q) {
            f32x4 acc[2][4];
            #pragma unroll
            for (int t = 0; t < 4; ++t) {
                float bb = bn0[wv * 128 + Q * 64 + t * 16 + m16];
                acc[0][t] = (f32x4){bb, bb, bb, bb};
                acc[1][t] = acc[0][t];
            }
            uint4 bwc[4], bwn[4];
            #pragma unroll
            for (int t = 0; t < 4; ++t)
                bwc[t] = F0[(0 * 64 + wv * 8 + Q * 4 + t) * 64 + lane];
            #pragma unroll
            for (int ks = 0; ks < 9; ++ks) {
                if (ks < 8) {
                    #pragma unroll
                    for (int t = 0; t < 4; ++t)
                        bwn[t] = F0[((ks + 1) * 64 + wv * 8 + Q * 4 + t) * 64 + lane];
                }
                #pragma unroll
                for (int mt = 0; mt < 2; ++mt) {
                    const _Float16* ap = (ks == 0)
                        ? &xlag[mt * 16 + m16][q16 * 8]
                        : &hA[0][mt * 16 + m16][(ks - 1) * 32 + q16 * 8];
                    half8 av = *(const half8*)ap;
                    #pragma unroll
                    for (int t = 0; t < 4; ++t)
                        acc[mt][t] = __builtin_amdgcn_mfma_f32_16x16x32_f16(
                            av, __builtin_bit_cast(half8, bwc[t]), acc[mt][t], 0, 0, 0);
                }
                #pragma unroll
                for (int t = 0; t < 4; ++t) bwc[t] = bwn[t];
            }
            #pragma unroll
            for (int mt = 0; mt < 2; ++mt) {
                #pragma unroll
                for (int t = 0; t < 4; ++t)
                    #pragma unroll
                    for (int rg = 0; rg < 4; ++rg)
                        scr[wv][q16 * 4 + rg][t * 16 + m16] = acc[mt][t][rg];
                __builtin_amdgcn_wave_barrier();
                int t2 = Q * 2 + mt;
                float hv[4];
                #pragma unroll
                for (int i = 0; i < 4; ++i) {
                    float4 g = *(const float4*)&scr[wv][m16][(q16 * 4 + i) * 4];
                    float c = sigm(g.y) * c0r[t2][i] + sigm(g.x) * ftanh(g.z);
                    c0r[t2][i] = c;
                    hv[i] = sigm(g.w) * ftanh(c);
                }
                __builtin_amdgcn_wave_barrier();
                hnew[t2] = make_uint2(packh2(hv[0], hv[1]), packh2(hv[2], hv[3]));
            }
        }
        __syncthreads();   // all L0 reads of hA[0]/xlag done
        #pragma unroll
        for (int Q = 0; Q < 2; ++Q)
            #pragma unroll
            for (int mt = 0; mt < 2; ++mt)
                *(uint2*)&hA[0][mt * 16 + m16][wv * 32 + Q * 16 + q16 * 4] = hnew[Q * 2 + mt];
        __syncthreads();   // hA[0] now h0(t)
        // ================= layer 1 =================
        #pragma unroll 1
        for (int Q = 0; Q < 2; ++Q) {
            f32x4 acc[2][4];
            #pragma unroll
            for (int t = 0; t < 4; ++t) {
                float bb = bn1[wv * 128 + Q * 64 + t * 16 + m16];
                acc[0][t] = (f32x4){bb, bb, bb, bb};
                acc[1][t] = acc[0][t];
            }
            uint4 bwc[4], bwn[4];
            #pragma unroll
            for (int t = 0; t < 4; ++t)
                bwc[t] = F1[(0 * 64 + wv * 8 + Q * 4 + t) * 64 + lane];
            #pragma unroll
            for (int ks = 0; ks < 16; ++ks) {
                if (ks < 15) {
                    #pragma unroll
                    for (int t = 0; t < 4; ++t)
                        bwn[t] = F1[((ks + 1) * 64 + wv * 8 + Q * 4 + t) * 64 + lane];
                }
                #pragma unroll
                for (int mt = 0; mt < 2; ++mt) {
                    const _Float16* ap = (ks < 8)
                        ? &hA[0][mt * 16 + m16][ks * 32 + q16 * 8]
                        : &hA[1][mt * 16 + m16][(ks - 8) * 32 + q16 * 8];
                    half8 av = *(const half8*)ap;
                    #pragma unroll
                    for (int t = 0; t < 4; ++t)
                        acc[mt][t] = __builtin_amdgcn_mfma_f32_16x16x32_f16(
                            av, __builtin_bit_cast(half8, bwc[t]), acc[mt][t], 0, 0, 0);
                }
                #pragma unroll
                for (int t = 0; t < 4; ++t) bwc[t] = bwn[t];
            }
            #pragma unroll
            for (int mt = 0; mt < 2; ++mt) {
                #pragma unroll
                for (int t = 0; t < 4; ++t)
                    #pragma unroll
                    for (int rg = 0; rg < 4; ++rg)
                        scr[wv][q16 * 4 + rg][t * 16 + m16] = acc[mt][t][rg];
                __builtin_amdgcn_wave_barrier();
                int t2 = Q * 2 + mt;
                float hv[4];
                #pragma unroll
                for (int i = 0; i < 4; ++i) {
                    float4 g = *(const float4*)&scr[wv][m16][(q16 * 4 + i) * 4];
                    float c = sigm(g.y) * c1r[t2][i] + sigm(g.x) * ftanh(g.z);
                    c1r[t2][i] = c;
                    hv[i] = sigm(g.w) * ftanh(c);
                }
                __builtin_amdgcn_wave_barrier();
                hnew[t2] = make_uint2(packh2(hv[0], hv[1]), packh2(hv[2], hv[3]));
            }
        }
        __syncthreads();   // all L1 reads of hA done
        #pragma unroll
        for (int Q = 0; Q < 2; ++Q)
            #pragma unroll
            for (int mt = 0; mt < 2; ++mt)
                *(uint2*)&hA[1][mt * 16 + m16][wv * 32 + Q * 16 + q16 * 4] = hnew[Q * 2 + mt];
        __syncthreads();   // hA[1] now h1(t)
        // ================= mu / sigma / sample (16 half-wave reducers) =================
        {
            const int half = lane >> 5, lane32 = lane & 31;
            #pragma unroll 1
            for (int it = 0; it < 2; ++it) {
                int rr = wv * 2 + half + it * 16;
                uint4 hu = *(const uint4*)&hA[1][rr][lane32 * 8];
                float4 wmA = *(const float4*)&w_mu[lane32 * 8];
                float4 wmB = *(const float4*)&w_mu[lane32 * 8 + 4];
                float4 wsA = *(const float4*)&w_sigma[lane32 * 8];
                float4 wsB = *(const float4*)&w_sigma[lane32 * 8 + 4];
                h2_t p0 = __builtin_bit_cast(h2_t, hu.x);
                h2_t p1 = __builtin_bit_cast(h2_t, hu.y);
                h2_t p2 = __builtin_bit_cast(h2_t, hu.z);
                h2_t p3 = __builtin_bit_cast(h2_t, hu.w);
                float h0f = (float)p0.x, h1f = (float)p0.y, h2f = (float)p1.x, h3f = (float)p1.y;
                float h4f = (float)p2.x, h5f = (float)p2.y, h6f = (float)p3.x, h7f = (float)p3.y;
                float sm = h0f * wmA.x + h1f * wmA.y + h2f * wmA.z + h3f * wmA.w
                         + h4f * wmB.x + h5f * wmB.y + h6f * wmB.z + h7f * wmB.w;
                float ss = h0f * wsA.x + h1f * wsA.y + h2f * wsA.z + h3f * wsA.w
                         + h4f * wsB.x + h5f * wsB.y + h6f * wsB.z + h7f * wsB.w;
                #pragma unroll
                for (int off = 16; off > 0; off >>= 1) {
                    sm += __shfl_down(sm, off, 32);
                    ss += __shfl_down(ss, off, 32);
                }
                if (lane32 == 0) {
                    float mu = sm + b_mu[0];
                    float sg = softplus(ss + b_sigma[0]);
                    int gr = gr0 + rr;
                    float smp = fmaf(sg, eps[st * GROWS + gr], mu);
                    atomicAdd(&accg[(gr / NS) * PRED + st], smp);
                    #pragma unroll
                    for (int f = NLAG - 1; f >= 1; --f) xlag[rr][f] = xlag[rr][f - 1];
                    xlag[rr][0] = (_Float16)smp;
                }
            }
        }
        __syncthreads();   // xlag(t+1) visible
    }
}

// ---------------- kernel 5: finalize ----------------
__global__ __launch_bounds__(256) void finalize_kernel(const float* __restrict__ ws,
                                                       float* __restrict__ out) {
    int i = blockIdx.x * blockDim.x + threadIdx.x;
    if (i < BATCH * PRED) {
        int b = i / PRED;
        out[i] = ws[OFF_ACC + i] * (1.0f / NS) * ws[OFF_SCALE + b] + ws[OFF_LOC + b];
    }
}

// ---------------- launch ----------------
extern "C" void kernel_launch(void* const* d_in, const int* in_sizes, int n_in,
                              void* d_out, int out_size, void* d_ws, size_t ws_size,
                              hipStream_t stream) {
    const float* targets = (const float*)d_in[0];
    const float* w_ih0 = (const float*)d_in[1];
    const float* w_hh0 = (const float*)d_in[2];
    const float* b_ih0 = (const float*)d_in[3];
    const float* b_hh0 = (const float*)d_in[4];
    const float* w_ih1 = (const float*)d_in[5];
    const float* w_hh1 = (const float*)d_in[6];
    const float* b_ih1 = (const float*)d_in[7];
    const float* b_hh1 = (const float*)d_in[8];
    const float* w_mu = (const float*)d_in[9];
    const float* b_mu = (const float*)d_in[10];
    const float* w_sigma = (const float*)d_in[11];
    const float* b_sigma = (const float*)d_in[12];
    const float* eps = (const float*)d_in[13];
    float* ws = (float*)d_ws;
    float* out = (float*)d_out;

    hipLaunchKernelGGL(prep_weights, dim3(1024), dim3(256), 0, stream,
                       w_ih0, w_hh0, b_ih0, b_hh0, w_ih1, w_hh1, b_ih1, b_hh1, ws);
    hipLaunchKernelGGL(prep_norm, dim3(BATCH), dim3(256), 0, stream, targets, ws);
    // Software pipeline: launch c runs enc0(chunk c) || enc1(chunk c-1).
    for (int c = 0; c <= NCHUNK; ++c) {
        int tc0 = (c < NCHUNK) ? c * TCHUNK : -1;
        int tc1 = (c >= 1) ? (c - 1) * TCHUNK : -1;
        hipLaunchKernelGGL(fused_enc, dim3(256), dim3(1024), 0, stream, ws, tc0, tc1);
    }
    hipLaunchKernelGGL(decoder_kernel, dim3(GROWS / RDEC), dim3(512), 0, stream,
                       ws, w_mu, b_mu, w_sigma, b_sigma, eps, ws);
    hipLaunchKernelGGL(finalize_kernel, dim3((BATCH * PRED + 255) / 256), dim3(256), 0,
                       stream, ws, out);
}